// Round 14
// baseline (457.968 us; speedup 1.0000x reference)
//
#include <hip/hip_runtime.h>
#include <math.h>

#define EPS_F 1e-6f
#define QSC   (0.125f * 1.44269504088896340736f)   // ATTN_SCALE * log2(e)

// weight-buffer offsets (elements) in whi/wlo
#define GATE_O 0
#define EWR_O  512
#define EWI_O  16896
#define QWR_O  33280
#define QWI_O  37376
#define KWR_O  41472
#define KWI_O  45568
#define VWR_O  49664
#define VWI_O  53760
#define CTX_O  57856
#define RES_O  74240
#define WTOT   90624

typedef __attribute__((ext_vector_type(8))) short short8;
typedef __attribute__((ext_vector_type(4))) float f32x4;
typedef unsigned short ushort_t;
typedef unsigned int uint_t;

__device__ __forceinline__ ushort_t f2bf(float x){
  uint_t u = __float_as_uint(x);
  u += 0x7fffu + ((u >> 16) & 1u);
  return (ushort_t)(u >> 16);
}
__device__ __forceinline__ float bf2f(ushort_t u){
  return __uint_as_float(((uint_t)u) << 16);
}
__device__ __forceinline__ uint_t pack2bf(float lo, float hi){
  return (uint_t)f2bf(lo) | ((uint_t)f2bf(hi) << 16);
}
// hardware packed f32->bf16 (RNE), 1 inst for 2 values
__device__ __forceinline__ uint_t cvtpk(float lo, float hi){
  uint_t r;
  asm("v_cvt_pk_bf16_f32 %0, %1, %2" : "=v"(r) : "v"(lo), "v"(hi));
  return r;
}

__device__ __forceinline__ float wave_sum64(float v){
  #pragma unroll
  for (int m = 32; m > 0; m >>= 1) v += __shfl_xor(v, m, 64);
  return v;
}
__device__ __forceinline__ float qsum16(float v){
  #pragma unroll
  for (int m = 1; m < 16; m <<= 1) v += __shfl_xor(v, m, 64);
  return v;
}

__device__ __forceinline__ short8 neg8(short8 v){
  uint4 u = *reinterpret_cast<uint4*>(&v);
  u.x ^= 0x80008000u; u.y ^= 0x80008000u; u.z ^= 0x80008000u; u.w ^= 0x80008000u;
  return *reinterpret_cast<short8*>(&u);
}
__device__ __forceinline__ short8 ld8(const ushort_t* __restrict__ p){
  return *reinterpret_cast<const short8*>(p);
}

#define MFMA(a,b,c) __builtin_amdgcn_mfma_f32_16x16x32_bf16((a),(b),(c),0,0,0)

// ============ weight conversion: fp32 -> bf16 hi/lo, fragment-ready ============
__global__ __launch_bounds__(256) void wconv_kernel(
    const float* __restrict__ gate_W, const float* __restrict__ exp_Wr,
    const float* __restrict__ exp_Wi,
    const float* __restrict__ q_Wr, const float* __restrict__ q_Wi,
    const float* __restrict__ k_Wr, const float* __restrict__ k_Wi,
    const float* __restrict__ v_Wr, const float* __restrict__ v_Wi,
    const float* __restrict__ ctx_W, const float* __restrict__ res_W,
    ushort_t* __restrict__ whi, ushort_t* __restrict__ wlo)
{
  int i = blockIdx.x * 256 + threadIdx.x;
  if (i >= WTOT) return;
  float v;
  if      (i < EWR_O) v = gate_W[i - GATE_O];
  else if (i < EWI_O) v = exp_Wr[i - EWR_O];
  else if (i < QWR_O) v = exp_Wi[i - EWI_O];
  else if (i < QWI_O) v = q_Wr[i - QWR_O];
  else if (i < KWR_O) v = q_Wi[i - QWI_O];
  else if (i < KWI_O) v = k_Wr[i - KWR_O];
  else if (i < VWR_O) v = k_Wi[i - KWI_O];
  else if (i < VWI_O) v = v_Wr[i - VWR_O];
  else if (i < CTX_O) v = v_Wi[i - VWI_O];
  else if (i < RES_O) v = ctx_W[i - CTX_O];
  else                v = res_W[i - RES_O];
  ushort_t h = f2bf(v);
  whi[i] = h;
  wlo[i] = f2bf(v - bf2f(h));
}

// ============ prep v3: MFMA everywhere, 4 waves/block, wave = col-tile ============
__global__ __launch_bounds__(256, 4) void prep_kernel(
    const float* __restrict__ z_real, const float* __restrict__ z_imag,
    const ushort_t* __restrict__ whi, const ushort_t* __restrict__ wlo,
    const float* __restrict__ gate_b,
    const float* __restrict__ ln_scale, const float* __restrict__ ln_shift,
    const float* __restrict__ mod_bias,
    const float* __restrict__ ctx_b, const float* __restrict__ res_b,
    ushort_t* __restrict__ qf, ushort_t* __restrict__ kf, ushort_t* __restrict__ vt,
    float* __restrict__ resb)
{
  const int tid  = threadIdx.x;
  const int lane = tid & 63;
  const int w    = tid >> 6;
  const int g    = lane >> 4;
  const int c    = lane & 15;
  const int row0 = blockIdx.x * 16;
  const int col  = w * 16 + c;
  const f32x4 z4 = {0.f, 0.f, 0.f, 0.f};

  __shared__ ushort_t s_xh[16][136];
  __shared__ ushort_t s_xl[16][136];
  __shared__ ushort_t s_a [16][136];
  __shared__ ushort_t s_tv[128][20];
  __shared__ float    s_red[4][16][2];

  {
    int rowl = tid >> 4;
    int col0 = (tid & 15) * 8;
    const float* src = (col0 < 64) ? (z_real + (size_t)(row0 + rowl) * 64 + col0)
                                   : (z_imag + (size_t)(row0 + rowl) * 64 + (col0 - 64));
    float4 a = *reinterpret_cast<const float4*>(src);
    float4 b = *reinterpret_cast<const float4*>(src + 4);
    float f[8] = {a.x, a.y, a.z, a.w, b.x, b.y, b.z, b.w};
    uint_t hp[4], lp[4];
    #pragma unroll
    for (int e = 0; e < 4; ++e){
      ushort_t h0 = f2bf(f[2*e]), h1 = f2bf(f[2*e+1]);
      hp[e] = (uint_t)h0 | ((uint_t)h1 << 16);
      lp[e] = (uint_t)f2bf(f[2*e]   - bf2f(h0)) |
              ((uint_t)f2bf(f[2*e+1] - bf2f(h1)) << 16);
    }
    uint4 uh; uh.x = hp[0]; uh.y = hp[1]; uh.z = hp[2]; uh.w = hp[3];
    uint4 ul; ul.x = lp[0]; ul.y = lp[1]; ul.z = lp[2]; ul.w = lp[3];
    *reinterpret_cast<uint4*>(&s_xh[rowl][col0]) = uh;
    *reinterpret_cast<uint4*>(&s_xl[rowl][col0]) = ul;
  }
  __syncthreads();

  short8 xh[4], xl[4];
  #pragma unroll
  for (int ks = 0; ks < 4; ++ks){
    xh[ks] = ld8(&s_xh[c][ks * 32 + g * 8]);
    xl[ks] = ld8(&s_xl[c][ks * 32 + g * 8]);
  }

  // ---- gate (compensated) ----
  float gwv[4];
  {
    f32x4 ga = z4;
    #pragma unroll
    for (int ks = 0; ks < 4; ++ks){
      int off = GATE_O + (c & 3) * 128 + ks * 32 + g * 8;
      short8 wh = ld8(whi + off), wl = ld8(wlo + off);
      ga = MFMA(xh[ks], wh, ga);
      ga = MFMA(xl[ks], wh, ga);
      ga = MFMA(xh[ks], wl, ga);
    }
    float gb = gate_b[c & 3];
    #pragma unroll
    for (int r = 0; r < 4; ++r){
      float le = ga[r] + gb;
      float mx = fmaxf(le, __shfl_xor(le, 1, 64));
      mx = fmaxf(mx, __shfl_xor(mx, 2, 64));
      float ev = __expf(le - mx);
      float sm = ev + __shfl_xor(ev, 1, 64);
      sm += __shfl_xor(sm, 2, 64);
      gwv[r] = ev / sm;
    }
  }

  // ---- MoE (compensated) ----
  f32x4 mrr = z4, mri = z4;
  #pragma unroll
  for (int e = 0; e < 4; ++e){
    float gwr[4];
    #pragma unroll
    for (int r = 0; r < 4; ++r) gwr[r] = __shfl(gwv[r], g * 16 + e, 64);
    f32x4 er = z4, ei = z4;
    #pragma unroll
    for (int ks = 0; ks < 2; ++ks){
      int boff = e * 4096 + col * 64 + ks * 32 + g * 8;
      short8 wrh = ld8(whi + EWR_O + boff);
      short8 wrl = ld8(wlo + EWR_O + boff);
      short8 wih = ld8(whi + EWI_O + boff);
      short8 wil = ld8(wlo + EWI_O + boff);
      short8 wihn = neg8(wih), wiln = neg8(wil);
      er = MFMA(xh[ks],   wrh, er);   ei = MFMA(xh[ks+2], wrh, ei);
      er = MFMA(xl[ks],   wrh, er);   ei = MFMA(xl[ks+2], wrh, ei);
      er = MFMA(xh[ks],   wrl, er);   ei = MFMA(xh[ks+2], wrl, ei);
      er = MFMA(xh[ks+2], wihn, er);  ei = MFMA(xh[ks],   wih, ei);
      er = MFMA(xl[ks+2], wihn, er);  ei = MFMA(xl[ks],   wih, ei);
      er = MFMA(xh[ks+2], wiln, er);  ei = MFMA(xh[ks],   wil, ei);
    }
    #pragma unroll
    for (int r = 0; r < 4; ++r){
      mrr[r] = fmaf(gwr[r], er[r], mrr[r]);
      mri[r] = fmaf(gwr[r], ei[r], mri[r]);
    }
  }

  // ---- ComplexLayerNorm (ddof=1) + ModReLU ----
  {
    float hh[4], mg[4];
    #pragma unroll
    for (int r = 0; r < 4; ++r){
      hh[r] = sqrtf(mrr[r] * mrr[r] + mri[r] * mri[r]);
      mg[r] = hh[r] + EPS_F;
    }
    #pragma unroll
    for (int r = 0; r < 4; ++r){
      float sx  = qsum16(mg[r]);
      float sxx = qsum16(mg[r] * mg[r]);
      if (c == 0){ s_red[w][g * 4 + r][0] = sx; s_red[w][g * 4 + r][1] = sxx; }
    }
    __syncthreads();
    float lsc = ln_scale[col], lsh = ln_shift[col], mb = mod_bias[col];
    #pragma unroll
    for (int r = 0; r < 4; ++r){
      int rr = g * 4 + r;
      float SX  = s_red[0][rr][0] + s_red[1][rr][0] + s_red[2][rr][0] + s_red[3][rr][0];
      float SXX = s_red[0][rr][1] + s_red[1][rr][1] + s_red[2][rr][1] + s_red[3][rr][1];
      float mean = SX * (1.0f / 64.0f);
      float var  = (SXX - SX * mean) * (1.0f / 63.0f);
      float istd = rsqrtf(var + EPS_F);
      float nm = (mg[r] - mean) * istd * lsc + lsh;
      float lr, li;
      if (hh[r] > 0.f){ float ih = 1.0f / hh[r]; lr = nm * mrr[r] * ih; li = nm * mri[r] * ih; }
      else            { lr = nm; li = 0.f; }
      float nrm = sqrtf(lr * lr + li * li) + EPS_F;
      float sf  = fmaxf(nrm + mb, 0.f) / nrm;
      s_a[rr][col]      = f2bf(lr * sf);
      s_a[rr][64 + col] = f2bf(li * sf);
    }
  }
  __syncthreads();

  // ---- ctx gate ----
  f32x4 cwa[2];
  #pragma unroll
  for (int ii = 0; ii < 2; ++ii){
    int ct8 = w + ii * 4;
    f32x4 a = z4;
    #pragma unroll
    for (int ks = 0; ks < 4; ++ks)
      a = MFMA(xh[ks], ld8(whi + CTX_O + (ct8 * 16 + c) * 128 + ks * 32 + g * 8), a);
    float cb = ctx_b[ct8 * 16 + c];
    #pragma unroll
    for (int r = 0; r < 4; ++r) cwa[ii][r] = 1.0f / (1.0f + __expf(-(a[r] + cb)));
  }

  // ---- residual ----
  #pragma unroll
  for (int ii = 0; ii < 2; ++ii){
    int ct8 = w + ii * 4;
    f32x4 a = z4;
    #pragma unroll
    for (int ks = 0; ks < 4; ++ks)
      a = MFMA(xh[ks], ld8(whi + RES_O + (ct8 * 16 + c) * 128 + ks * 32 + g * 8), a);
    float rb = res_b[ct8 * 16 + c];
    #pragma unroll
    for (int r = 0; r < 4; ++r)
      resb[(size_t)(row0 + 4 * g + r) * 128 + ct8 * 16 + c] = 0.1f * (a[r] + rb);
  }

  // ---- QKV ----
  short8 ar_[2], ai_[2], ain_[2];
  #pragma unroll
  for (int ks = 0; ks < 2; ++ks){
    ar_[ks]  = ld8(&s_a[c][ks * 32 + g * 8]);
    ai_[ks]  = ld8(&s_a[c][64 + ks * 32 + g * 8]);
    ain_[ks] = neg8(ai_[ks]);
  }

  #pragma unroll
  for (int mat = 0; mat < 3; ++mat){
    int roff = (mat == 0) ? QWR_O : (mat == 1) ? KWR_O : VWR_O;
    int ioff = (mat == 0) ? QWI_O : (mat == 1) ? KWI_O : VWI_O;
    f32x4 orr = z4, oii = z4;
    #pragma unroll
    for (int ks = 0; ks < 2; ++ks){
      int boff = col * 64 + ks * 32 + g * 8;
      short8 wrh = ld8(whi + roff + boff);
      short8 wrl = ld8(wlo + roff + boff);
      short8 wih = ld8(whi + ioff + boff);
      short8 wil = ld8(wlo + ioff + boff);
      orr = MFMA(ar_[ks],  wrh, orr);  oii = MFMA(ai_[ks], wrh, oii);
      orr = MFMA(ar_[ks],  wrl, orr);  oii = MFMA(ai_[ks], wrl, oii);
      orr = MFMA(ain_[ks], wih, orr);  oii = MFMA(ar_[ks], wih, oii);
      orr = MFMA(ain_[ks], wil, orr);  oii = MFMA(ar_[ks], wil, oii);
    }
    if (mat == 0){
      #pragma unroll
      for (int r = 0; r < 4; ++r){
        size_t row = row0 + 4 * g + r;
        qf[row * 128 + col]      = f2bf(orr[r] * cwa[0][r] * QSC);
        qf[row * 128 + 64 + col] = f2bf(oii[r] * cwa[1][r] * QSC);
      }
    } else if (mat == 1){
      #pragma unroll
      for (int r = 0; r < 4; ++r){
        size_t row = row0 + 4 * g + r;
        kf[row * 128 + col]      = f2bf(orr[r]);
        kf[row * 128 + 64 + col] = f2bf(oii[r]);
      }
    } else {
      #pragma unroll
      for (int r = 0; r < 4; ++r){
        s_tv[col][4 * g + r]      = f2bf(orr[r]);
        s_tv[64 + col][4 * g + r] = f2bf(oii[r]);
      }
    }
  }
  __syncthreads();

  {
    int d = tid >> 1, half = tid & 1;
    uint2 t0 = *reinterpret_cast<const uint2*>(&s_tv[d][half * 8]);
    uint2 t1 = *reinterpret_cast<const uint2*>(&s_tv[d][half * 8 + 4]);
    uint4 o; o.x = t0.x; o.y = t0.y; o.z = t1.x; o.w = t1.y;
    *reinterpret_cast<uint4*>(vt + (size_t)d * 8192 + row0 + half * 8) = o;
  }
}

// ---- online softmax for one 16-q half; THR=8 defer-max (exact bookkeeping) ----
__device__ __forceinline__ short8 sm_half(
    const f32x4& s0, const f32x4& s1, float& mrun, float& lrun,
    f32x4* __restrict__ oacc, uint_t* __restrict__ prow, int g)
{
  float t0 = fmaxf(fmaxf(fmaxf(s0[0], s0[1]), fmaxf(s0[2], s0[3])),
                   fmaxf(fmaxf(s1[0], s1[1]), fmaxf(s1[2], s1[3])));
  t0 = fmaxf(t0, __shfl_xor(t0, 16, 64));
  t0 = fmaxf(t0, __shfl_xor(t0, 32, 64));
  // defer-max: rescale only when tile max exceeds running max by >8
  // (exp2 domain -> p bounded by 2^8; l and O stay consistent with mrun)
  if (__any(t0 > mrun + 8.0f)){
    float mnew = fmaxf(mrun, t0);
    float fac  = exp2f(mrun - mnew);
    lrun *= fac;
    #pragma unroll
    for (int dt = 0; dt < 8; ++dt){
      oacc[dt][0] *= fac; oacc[dt][1] *= fac; oacc[dt][2] *= fac; oacc[dt][3] *= fac;
    }
    mrun = mnew;
  }
  float p00 = exp2f(s0[0] - mrun), p01 = exp2f(s0[1] - mrun);
  float p02 = exp2f(s0[2] - mrun), p03 = exp2f(s0[3] - mrun);
  float p10 = exp2f(s1[0] - mrun), p11 = exp2f(s1[1] - mrun);
  float p12 = exp2f(s1[2] - mrun), p13 = exp2f(s1[3] - mrun);
  float ps = ((p00 + p01) + (p02 + p03)) + ((p10 + p11) + (p12 + p13));
  ps += __shfl_xor(ps, 16, 64);
  ps += __shfl_xor(ps, 32, 64);
  lrun += ps;
  uint2 w0; w0.x = cvtpk(p00, p01); w0.y = cvtpk(p02, p03);
  uint2 w1; w1.x = cvtpk(p10, p11); w1.y = cvtpk(p12, p13);
  *reinterpret_cast<uint2*>(prow + 2 * g)     = w0;
  *reinterpret_cast<uint2*>(prow + 8 + 2 * g) = w1;
  return *reinterpret_cast<const short8*>(prow + 4 * g);
}

// ---- MFMA flash attention: 32 q/wave, XOR-swizzled K/V LDS tiles ----
// (round-13 structure; ONLY change: launch_bounds 3 -> 6 waves/EU.
//  VGPR demand is 80 <= ~85 cap, LDS 26.6KB allows 6 blocks/CU.
//  reg-prefetch remains BANNED: NaN in r11/r12.)
template<int NCH_T>
__global__ __launch_bounds__(256, 6) void attn_mfma(
    const ushort_t* __restrict__ qf, const ushort_t* __restrict__ kf, const ushort_t* __restrict__ vt,
    ushort_t* __restrict__ pacc, float* __restrict__ pm, float* __restrict__ pl)
{
  constexpr int CHUNK_T = 8192 / NCH_T;
  constexpr int TILES_T = CHUNK_T / 32;

  const int tid  = threadIdx.x;
  const int lane = tid & 63;
  const int w    = tid >> 6;
  const int g    = lane >> 4;
  const int hl   = lane & 15;
  const int qb   = blockIdx.x & 63;
  const int jc   = blockIdx.x >> 6;
  const int qw   = qb * 128 + w * 32;
  const int qrA  = qw + hl;
  const int qrB  = qw + 16 + hl;

  __shared__ ushort_t s_k[32][128];    // XOR-swizzled: col ^= (row&7)*8
  __shared__ ushort_t s_vt[128][32];   // XOR-swizzled: col ^= (row&3)*8
  __shared__ uint_t   s_p32[4][2][16][20];

  const int kjj0 = tid >> 4;
  const int kkk  = (tid & 15) * 8;
  const int vd0  = tid >> 2;
  const int vjo  = (tid & 3) * 8;
  const int jstart = jc * CHUNK_T;

  short8 qfA[4], qfB[4];
  #pragma unroll
  for (int kt = 0; kt < 4; ++kt){
    qfA[kt] = ld8(qf + (size_t)qrA * 128 + kt * 32 + g * 8);
    qfB[kt] = ld8(qf + (size_t)qrB * 128 + kt * 32 + g * 8);
  }

  f32x4 oA[8], oB[8];
  #pragma unroll
  for (int dt = 0; dt < 8; ++dt){
    oA[dt] = (f32x4){0.f, 0.f, 0.f, 0.f};
    oB[dt] = (f32x4){0.f, 0.f, 0.f, 0.f};
  }
  float mA = -3.0e38f, lA = 0.f, mB = -3.0e38f, lB = 0.f;

  for (int t = 0; t < TILES_T; ++t){
    const int jb = jstart + t * 32;
    __syncthreads();
    #pragma unroll
    for (int i = 0; i < 2; ++i){
      int kr = kjj0 + i * 16;
      *reinterpret_cast<uint4*>(&s_k[kr][kkk ^ ((kr & 7) * 8)]) =
          *reinterpret_cast<const uint4*>(kf + (size_t)(jb + kr) * 128 + kkk);
      int vr = vd0 + i * 64;
      *reinterpret_cast<uint4*>(&s_vt[vr][vjo ^ ((vr & 3) * 8)]) =
          *reinterpret_cast<const uint4*>(vt + (size_t)vr * 8192 + jb + vjo);
    }
    __syncthreads();

    // ---- QK^T for both q-halves; each K fragment read feeds 2 MFMAs ----
    f32x4 sA[2], sB[2];
    #pragma unroll
    for (int jt = 0; jt < 2; ++jt){
      sA[jt] = (f32x4){0.f, 0.f, 0.f, 0.f};
      sB[jt] = (f32x4){0.f, 0.f, 0.f, 0.f};
      #pragma unroll
      for (int kt = 0; kt < 4; ++kt){
        short8 kfr = ld8(&s_k[jt * 16 + hl][(kt * 32 + g * 8) ^ ((hl & 7) * 8)]);
        sA[jt] = __builtin_amdgcn_mfma_f32_16x16x32_bf16(kfr, qfA[kt], sA[jt], 0, 0, 0);
        sB[jt] = __builtin_amdgcn_mfma_f32_16x16x32_bf16(kfr, qfB[kt], sB[jt], 0, 0, 0);
      }
    }

    short8 pfA = sm_half(sA[0], sA[1], mA, lA, oA, &s_p32[w][0][hl][0], g);
    short8 pfB = sm_half(sB[0], sB[1], mB, lB, oB, &s_p32[w][1][hl][0], g);

    // ---- PV for both halves; each V fragment read feeds 2 MFMAs ----
    #pragma unroll
    for (int dt = 0; dt < 8; ++dt){
      short8 vfr = ld8(&s_vt[dt * 16 + hl][(g * 8) ^ ((hl & 3) * 8)]);
      oA[dt] = __builtin_amdgcn_mfma_f32_16x16x32_bf16(vfr, pfA, oA[dt], 0, 0, 0);
      oB[dt] = __builtin_amdgcn_mfma_f32_16x16x32_bf16(vfr, pfB, oB[dt], 0, 0, 0);
    }
  }

  // ---- write partials (bf16, pair-packed 8B stores) ----
  #pragma unroll
  for (int dt = 0; dt < 8; ++dt){
    uint2 a;
    a.x = cvtpk(oA[dt][0], oA[dt][1]);
    a.y = cvtpk(oA[dt][2], oA[dt][3]);
    *reinterpret_cast<uint2*>(pacc + ((size_t)jc * 8192 + qrA) * 128 + dt * 16 + 4 * g) = a;
    uint2 b;
    b.x = cvtpk(oB[dt][0], oB[dt][1]);
    b.y = cvtpk(oB[dt][2], oB[dt][3]);
    *reinterpret_cast<uint2*>(pacc + ((size_t)jc * 8192 + qrB) * 128 + dt * 16 + 4 * g) = b;
  }
  if (g == 0){
    pm[jc * 8192 + qrA] = mA;  pl[jc * 8192 + qrA] = lA;
    pm[jc * 8192 + qrB] = mB;  pl[jc * 8192 + qrB] = lB;
  }
}

// ---- combine chunk partials + residual + halt/stack heads ----
template<int NCH_T>
__global__ __launch_bounds__(256, 1) void combine_kernel(
    const ushort_t* __restrict__ pacc, const float* __restrict__ pm, const float* __restrict__ pl,
    const float* __restrict__ resb,
    const float* __restrict__ halt_W, const float* __restrict__ halt_b,
    const float* __restrict__ stack_W, const float* __restrict__ stack_b,
    float* __restrict__ out)
{
  const int tid  = threadIdx.x;
  const int lane = tid & 63;
  const int w    = tid >> 6;
  const int q    = blockIdx.x * 4 + w;

  float mv[NCH_T], M = -3.0e38f;
  #pragma unroll
  for (int c = 0; c < NCH_T; ++c){ mv[c] = pm[c * 8192 + q]; M = fmaxf(M, mv[c]); }
  float f[NCH_T]; float L = 0.f;
  #pragma unroll
  for (int c = 0; c < NCH_T; ++c){ f[c] = exp2f(mv[c] - M); L += pl[c * 8192 + q] * f[c]; }
  float invL = 1.0f / L;

  float o0 = 0.f, o1 = 0.f;
  #pragma unroll
  for (int c = 0; c < NCH_T; ++c){
    const ushort_t* pa = pacc + ((size_t)c * 8192 + q) * 128;
    o0 += bf2f(pa[lane])      * f[c];
    o1 += bf2f(pa[64 + lane]) * f[c];
  }
  o0 = o0 * invL + resb[(size_t)q * 128 + lane];
  o1 = o1 * invL + resb[(size_t)q * 128 + 64 + lane];
  out[(size_t)q * 64 + lane] = o0;
  out[(size_t)8192 * 64 + (size_t)q * 64 + lane] = o1;

  float ssq  = wave_sum64(o0 * o0 + o1 * o1);
  float invn = 1.0f / (sqrtf(ssq) + 1e-6f);
  float zn0 = o0 * invn, zn1 = o1 * invn;
  float hp = wave_sum64(zn0 * halt_W[lane]        + zn1 * halt_W[64 + lane]);
  float s0 = wave_sum64(zn0 * stack_W[lane]       + zn1 * stack_W[64 + lane]);
  float s1 = wave_sum64(zn0 * stack_W[128 + lane] + zn1 * stack_W[192 + lane]);
  float s2 = wave_sum64(zn0 * stack_W[256 + lane] + zn1 * stack_W[320 + lane]);
  if (lane == 0){
    out[1048576 + q] = hp + halt_b[0];
    out[1056768 + (size_t)q * 3 + 0] = s0 + stack_b[0];
    out[1056768 + (size_t)q * 3 + 1] = s1 + stack_b[1];
    out[1056768 + (size_t)q * 3 + 2] = s2 + stack_b[2];
  }
}

extern "C" void kernel_launch(void* const* d_in, const int* in_sizes, int n_in,
                              void* d_out, int out_size, void* d_ws, size_t ws_size,
                              hipStream_t stream){
  const float* z_real  = (const float*)d_in[0];
  const float* z_imag  = (const float*)d_in[1];
  const float* gate_W  = (const float*)d_in[2];
  const float* gate_b  = (const float*)d_in[3];
  const float* exp_Wr  = (const float*)d_in[4];
  const float* exp_Wi  = (const float*)d_in[5];
  const float* ln_scale= (const float*)d_in[6];
  const float* ln_shift= (const float*)d_in[7];
  const float* mod_bias= (const float*)d_in[8];
  const float* q_Wr    = (const float*)d_in[9];
  const float* q_Wi    = (const float*)d_in[10];
  const float* k_Wr    = (const float*)d_in[11];
  const float* k_Wi    = (const float*)d_in[12];
  const float* v_Wr    = (const float*)d_in[13];
  const float* v_Wi    = (const float*)d_in[14];
  const float* ctx_W   = (const float*)d_in[15];
  const float* ctx_b   = (const float*)d_in[16];
  const float* res_W   = (const float*)d_in[17];
  const float* res_b   = (const float*)d_in[18];
  const float* halt_W  = (const float*)d_in[19];
  const float* halt_b  = (const float*)d_in[20];
  const float* stack_W = (const float*)d_in[21];
  const float* stack_b = (const float*)d_in[22];

  auto need = [&](int nch)->size_t{
    size_t b = (size_t)3 * 8192 * 128 * 2;                       // qbf,kbf,vtb bf16
    b += (size_t)8192 * 128 * 4;                                 // resb fp32
    b += (size_t)nch * 8192 * 128 * 2;                           // pacc bf16
    b += (size_t)2 * nch * 8192 * 4;                             // pm, pl
    b += (size_t)2 * WTOT * 2;                                   // whi, wlo
    return b;
  };
  const int nch = (ws_size >= need(32)) ? 32 : (ws_size >= need(16)) ? 16 : 8;

  ushort_t* qbf = (ushort_t*)d_ws;
  ushort_t* kbf = qbf + (size_t)8192*128;
  ushort_t* vtb = kbf + (size_t)8192*128;
  float* resb = (float*)(vtb + (size_t)8192*128);
  ushort_t* pacc = (ushort_t*)(resb + (size_t)8192*128);
  float* pm   = (float*)(pacc + (size_t)nch*8192*128);
  float* pl   = pm   + (size_t)nch*8192;
  ushort_t* whi = (ushort_t*)(pl + (size_t)nch*8192);
  ushort_t* wlo = whi + WTOT;

  wconv_kernel<<<(WTOT + 255) / 256, 256, 0, stream>>>(gate_W, exp_Wr, exp_Wi,
      q_Wr, q_Wi, k_Wr, k_Wi, v_Wr, v_Wi, ctx_W, res_W, whi, wlo);
  prep_kernel<<<512, 256, 0, stream>>>(z_real, z_imag, whi, wlo, gate_b,
      ln_scale, ln_shift, mod_bias, ctx_b, res_b, qbf, kbf, vtb, resb);
  if (nch == 32){
    attn_mfma<32><<<64*32, 256, 0, stream>>>(qbf, kbf, vtb, pacc, pm, pl);
    combine_kernel<32><<<2048, 256, 0, stream>>>(pacc, pm, pl, resb,
        halt_W, halt_b, stack_W, stack_b, (float*)d_out);
  } else if (nch == 16){
    attn_mfma<16><<<64*16, 256, 0, stream>>>(qbf, kbf, vtb, pacc, pm, pl);
    combine_kernel<16><<<2048, 256, 0, stream>>>(pacc, pm, pl, resb,
        halt_W, halt_b, stack_W, stack_b, (float*)d_out);
  } else {
    attn_mfma<8><<<64*8, 256, 0, stream>>>(qbf, kbf, vtb, pacc, pm, pl);
    combine_kernel<8><<<2048, 256, 0, stream>>>(pacc, pm, pl, resb,
        halt_W, halt_b, stack_W, stack_b, (float*)d_out);
  }
}

// Round 15
// 131.011 us; speedup vs baseline: 3.4956x; 3.4956x over previous
//
#include <hip/hip_runtime.h>
#include <math.h>

#define EPS_F 1e-6f
#define QSC   (0.125f * 1.44269504088896340736f)   // ATTN_SCALE * log2(e)

// weight-buffer offsets (elements) in whi/wlo
#define GATE_O 0
#define EWR_O  512
#define EWI_O  16896
#define QWR_O  33280
#define QWI_O  37376
#define KWR_O  41472
#define KWI_O  45568
#define VWR_O  49664
#define VWI_O  53760
#define CTX_O  57856
#define RES_O  74240
#define WTOT   90624

typedef __attribute__((ext_vector_type(8))) short short8;
typedef __attribute__((ext_vector_type(4))) float f32x4;
typedef unsigned short ushort_t;
typedef unsigned int uint_t;

__device__ __forceinline__ ushort_t f2bf(float x){
  uint_t u = __float_as_uint(x);
  u += 0x7fffu + ((u >> 16) & 1u);
  return (ushort_t)(u >> 16);
}
__device__ __forceinline__ float bf2f(ushort_t u){
  return __uint_as_float(((uint_t)u) << 16);
}
__device__ __forceinline__ uint_t pack2bf(float lo, float hi){
  return (uint_t)f2bf(lo) | ((uint_t)f2bf(hi) << 16);
}
// hardware packed f32->bf16 (RNE), 1 inst for 2 values
__device__ __forceinline__ uint_t cvtpk(float lo, float hi){
  uint_t r;
  asm("v_cvt_pk_bf16_f32 %0, %1, %2" : "=v"(r) : "v"(lo), "v"(hi));
  return r;
}

__device__ __forceinline__ float wave_sum64(float v){
  #pragma unroll
  for (int m = 32; m > 0; m >>= 1) v += __shfl_xor(v, m, 64);
  return v;
}
__device__ __forceinline__ float qsum16(float v){
  #pragma unroll
  for (int m = 1; m < 16; m <<= 1) v += __shfl_xor(v, m, 64);
  return v;
}

__device__ __forceinline__ short8 neg8(short8 v){
  uint4 u = *reinterpret_cast<uint4*>(&v);
  u.x ^= 0x80008000u; u.y ^= 0x80008000u; u.z ^= 0x80008000u; u.w ^= 0x80008000u;
  return *reinterpret_cast<short8*>(&u);
}
__device__ __forceinline__ short8 ld8(const ushort_t* __restrict__ p){
  return *reinterpret_cast<const short8*>(p);
}

#define MFMA(a,b,c) __builtin_amdgcn_mfma_f32_16x16x32_bf16((a),(b),(c),0,0,0)

// ============ weight conversion: fp32 -> bf16 hi/lo, fragment-ready ============
__global__ __launch_bounds__(256) void wconv_kernel(
    const float* __restrict__ gate_W, const float* __restrict__ exp_Wr,
    const float* __restrict__ exp_Wi,
    const float* __restrict__ q_Wr, const float* __restrict__ q_Wi,
    const float* __restrict__ k_Wr, const float* __restrict__ k_Wi,
    const float* __restrict__ v_Wr, const float* __restrict__ v_Wi,
    const float* __restrict__ ctx_W, const float* __restrict__ res_W,
    ushort_t* __restrict__ whi, ushort_t* __restrict__ wlo)
{
  int i = blockIdx.x * 256 + threadIdx.x;
  if (i >= WTOT) return;
  float v;
  if      (i < EWR_O) v = gate_W[i - GATE_O];
  else if (i < EWI_O) v = exp_Wr[i - EWR_O];
  else if (i < QWR_O) v = exp_Wi[i - EWI_O];
  else if (i < QWI_O) v = q_Wr[i - QWR_O];
  else if (i < KWR_O) v = q_Wi[i - QWI_O];
  else if (i < KWI_O) v = k_Wr[i - KWR_O];
  else if (i < VWR_O) v = k_Wi[i - KWI_O];
  else if (i < VWI_O) v = v_Wr[i - VWR_O];
  else if (i < CTX_O) v = v_Wi[i - VWI_O];
  else if (i < RES_O) v = ctx_W[i - CTX_O];
  else                v = res_W[i - RES_O];
  ushort_t h = f2bf(v);
  whi[i] = h;
  wlo[i] = f2bf(v - bf2f(h));
}

// ============ prep v3: MFMA everywhere, 4 waves/block, wave = col-tile ============
__global__ __launch_bounds__(256, 4) void prep_kernel(
    const float* __restrict__ z_real, const float* __restrict__ z_imag,
    const ushort_t* __restrict__ whi, const ushort_t* __restrict__ wlo,
    const float* __restrict__ gate_b,
    const float* __restrict__ ln_scale, const float* __restrict__ ln_shift,
    const float* __restrict__ mod_bias,
    const float* __restrict__ ctx_b, const float* __restrict__ res_b,
    ushort_t* __restrict__ qf, ushort_t* __restrict__ kf, ushort_t* __restrict__ vt,
    float* __restrict__ resb)
{
  const int tid  = threadIdx.x;
  const int lane = tid & 63;
  const int w    = tid >> 6;
  const int g    = lane >> 4;
  const int c    = lane & 15;
  const int row0 = blockIdx.x * 16;
  const int col  = w * 16 + c;
  const f32x4 z4 = {0.f, 0.f, 0.f, 0.f};

  __shared__ ushort_t s_xh[16][136];
  __shared__ ushort_t s_xl[16][136];
  __shared__ ushort_t s_a [16][136];
  __shared__ ushort_t s_tv[128][20];
  __shared__ float    s_red[4][16][2];

  {
    int rowl = tid >> 4;
    int col0 = (tid & 15) * 8;
    const float* src = (col0 < 64) ? (z_real + (size_t)(row0 + rowl) * 64 + col0)
                                   : (z_imag + (size_t)(row0 + rowl) * 64 + (col0 - 64));
    float4 a = *reinterpret_cast<const float4*>(src);
    float4 b = *reinterpret_cast<const float4*>(src + 4);
    float f[8] = {a.x, a.y, a.z, a.w, b.x, b.y, b.z, b.w};
    uint_t hp[4], lp[4];
    #pragma unroll
    for (int e = 0; e < 4; ++e){
      ushort_t h0 = f2bf(f[2*e]), h1 = f2bf(f[2*e+1]);
      hp[e] = (uint_t)h0 | ((uint_t)h1 << 16);
      lp[e] = (uint_t)f2bf(f[2*e]   - bf2f(h0)) |
              ((uint_t)f2bf(f[2*e+1] - bf2f(h1)) << 16);
    }
    uint4 uh; uh.x = hp[0]; uh.y = hp[1]; uh.z = hp[2]; uh.w = hp[3];
    uint4 ul; ul.x = lp[0]; ul.y = lp[1]; ul.z = lp[2]; ul.w = lp[3];
    *reinterpret_cast<uint4*>(&s_xh[rowl][col0]) = uh;
    *reinterpret_cast<uint4*>(&s_xl[rowl][col0]) = ul;
  }
  __syncthreads();

  short8 xh[4], xl[4];
  #pragma unroll
  for (int ks = 0; ks < 4; ++ks){
    xh[ks] = ld8(&s_xh[c][ks * 32 + g * 8]);
    xl[ks] = ld8(&s_xl[c][ks * 32 + g * 8]);
  }

  // ---- gate (compensated) ----
  float gwv[4];
  {
    f32x4 ga = z4;
    #pragma unroll
    for (int ks = 0; ks < 4; ++ks){
      int off = GATE_O + (c & 3) * 128 + ks * 32 + g * 8;
      short8 wh = ld8(whi + off), wl = ld8(wlo + off);
      ga = MFMA(xh[ks], wh, ga);
      ga = MFMA(xl[ks], wh, ga);
      ga = MFMA(xh[ks], wl, ga);
    }
    float gb = gate_b[c & 3];
    #pragma unroll
    for (int r = 0; r < 4; ++r){
      float le = ga[r] + gb;
      float mx = fmaxf(le, __shfl_xor(le, 1, 64));
      mx = fmaxf(mx, __shfl_xor(mx, 2, 64));
      float ev = __expf(le - mx);
      float sm = ev + __shfl_xor(ev, 1, 64);
      sm += __shfl_xor(sm, 2, 64);
      gwv[r] = ev / sm;
    }
  }

  // ---- MoE (compensated) ----
  f32x4 mrr = z4, mri = z4;
  #pragma unroll
  for (int e = 0; e < 4; ++e){
    float gwr[4];
    #pragma unroll
    for (int r = 0; r < 4; ++r) gwr[r] = __shfl(gwv[r], g * 16 + e, 64);
    f32x4 er = z4, ei = z4;
    #pragma unroll
    for (int ks = 0; ks < 2; ++ks){
      int boff = e * 4096 + col * 64 + ks * 32 + g * 8;
      short8 wrh = ld8(whi + EWR_O + boff);
      short8 wrl = ld8(wlo + EWR_O + boff);
      short8 wih = ld8(whi + EWI_O + boff);
      short8 wil = ld8(wlo + EWI_O + boff);
      short8 wihn = neg8(wih), wiln = neg8(wil);
      er = MFMA(xh[ks],   wrh, er);   ei = MFMA(xh[ks+2], wrh, ei);
      er = MFMA(xl[ks],   wrh, er);   ei = MFMA(xl[ks+2], wrh, ei);
      er = MFMA(xh[ks],   wrl, er);   ei = MFMA(xh[ks+2], wrl, ei);
      er = MFMA(xh[ks+2], wihn, er);  ei = MFMA(xh[ks],   wih, ei);
      er = MFMA(xl[ks+2], wihn, er);  ei = MFMA(xl[ks],   wih, ei);
      er = MFMA(xh[ks+2], wiln, er);  ei = MFMA(xh[ks],   wil, ei);
    }
    #pragma unroll
    for (int r = 0; r < 4; ++r){
      mrr[r] = fmaf(gwr[r], er[r], mrr[r]);
      mri[r] = fmaf(gwr[r], ei[r], mri[r]);
    }
  }

  // ---- ComplexLayerNorm (ddof=1) + ModReLU ----
  {
    float hh[4], mg[4];
    #pragma unroll
    for (int r = 0; r < 4; ++r){
      hh[r] = sqrtf(mrr[r] * mrr[r] + mri[r] * mri[r]);
      mg[r] = hh[r] + EPS_F;
    }
    #pragma unroll
    for (int r = 0; r < 4; ++r){
      float sx  = qsum16(mg[r]);
      float sxx = qsum16(mg[r] * mg[r]);
      if (c == 0){ s_red[w][g * 4 + r][0] = sx; s_red[w][g * 4 + r][1] = sxx; }
    }
    __syncthreads();
    float lsc = ln_scale[col], lsh = ln_shift[col], mb = mod_bias[col];
    #pragma unroll
    for (int r = 0; r < 4; ++r){
      int rr = g * 4 + r;
      float SX  = s_red[0][rr][0] + s_red[1][rr][0] + s_red[2][rr][0] + s_red[3][rr][0];
      float SXX = s_red[0][rr][1] + s_red[1][rr][1] + s_red[2][rr][1] + s_red[3][rr][1];
      float mean = SX * (1.0f / 64.0f);
      float var  = (SXX - SX * mean) * (1.0f / 63.0f);
      float istd = rsqrtf(var + EPS_F);
      float nm = (mg[r] - mean) * istd * lsc + lsh;
      float lr, li;
      if (hh[r] > 0.f){ float ih = 1.0f / hh[r]; lr = nm * mrr[r] * ih; li = nm * mri[r] * ih; }
      else            { lr = nm; li = 0.f; }
      float nrm = sqrtf(lr * lr + li * li) + EPS_F;
      float sf  = fmaxf(nrm + mb, 0.f) / nrm;
      s_a[rr][col]      = f2bf(lr * sf);
      s_a[rr][64 + col] = f2bf(li * sf);
    }
  }
  __syncthreads();

  // ---- ctx gate ----
  f32x4 cwa[2];
  #pragma unroll
  for (int ii = 0; ii < 2; ++ii){
    int ct8 = w + ii * 4;
    f32x4 a = z4;
    #pragma unroll
    for (int ks = 0; ks < 4; ++ks)
      a = MFMA(xh[ks], ld8(whi + CTX_O + (ct8 * 16 + c) * 128 + ks * 32 + g * 8), a);
    float cb = ctx_b[ct8 * 16 + c];
    #pragma unroll
    for (int r = 0; r < 4; ++r) cwa[ii][r] = 1.0f / (1.0f + __expf(-(a[r] + cb)));
  }

  // ---- residual ----
  #pragma unroll
  for (int ii = 0; ii < 2; ++ii){
    int ct8 = w + ii * 4;
    f32x4 a = z4;
    #pragma unroll
    for (int ks = 0; ks < 4; ++ks)
      a = MFMA(xh[ks], ld8(whi + RES_O + (ct8 * 16 + c) * 128 + ks * 32 + g * 8), a);
    float rb = res_b[ct8 * 16 + c];
    #pragma unroll
    for (int r = 0; r < 4; ++r)
      resb[(size_t)(row0 + 4 * g + r) * 128 + ct8 * 16 + c] = 0.1f * (a[r] + rb);
  }

  // ---- QKV ----
  short8 ar_[2], ai_[2], ain_[2];
  #pragma unroll
  for (int ks = 0; ks < 2; ++ks){
    ar_[ks]  = ld8(&s_a[c][ks * 32 + g * 8]);
    ai_[ks]  = ld8(&s_a[c][64 + ks * 32 + g * 8]);
    ain_[ks] = neg8(ai_[ks]);
  }

  #pragma unroll
  for (int mat = 0; mat < 3; ++mat){
    int roff = (mat == 0) ? QWR_O : (mat == 1) ? KWR_O : VWR_O;
    int ioff = (mat == 0) ? QWI_O : (mat == 1) ? KWI_O : VWI_O;
    f32x4 orr = z4, oii = z4;
    #pragma unroll
    for (int ks = 0; ks < 2; ++ks){
      int boff = col * 64 + ks * 32 + g * 8;
      short8 wrh = ld8(whi + roff + boff);
      short8 wrl = ld8(wlo + roff + boff);
      short8 wih = ld8(whi + ioff + boff);
      short8 wil = ld8(wlo + ioff + boff);
      orr = MFMA(ar_[ks],  wrh, orr);  oii = MFMA(ai_[ks], wrh, oii);
      orr = MFMA(ar_[ks],  wrl, orr);  oii = MFMA(ai_[ks], wrl, oii);
      orr = MFMA(ain_[ks], wih, orr);  oii = MFMA(ar_[ks], wih, oii);
      orr = MFMA(ain_[ks], wil, orr);  oii = MFMA(ar_[ks], wil, oii);
    }
    if (mat == 0){
      #pragma unroll
      for (int r = 0; r < 4; ++r){
        size_t row = row0 + 4 * g + r;
        qf[row * 128 + col]      = f2bf(orr[r] * cwa[0][r] * QSC);
        qf[row * 128 + 64 + col] = f2bf(oii[r] * cwa[1][r] * QSC);
      }
    } else if (mat == 1){
      #pragma unroll
      for (int r = 0; r < 4; ++r){
        size_t row = row0 + 4 * g + r;
        kf[row * 128 + col]      = f2bf(orr[r]);
        kf[row * 128 + 64 + col] = f2bf(oii[r]);
      }
    } else {
      #pragma unroll
      for (int r = 0; r < 4; ++r){
        s_tv[col][4 * g + r]      = f2bf(orr[r]);
        s_tv[64 + col][4 * g + r] = f2bf(oii[r]);
      }
    }
  }
  __syncthreads();

  {
    int d = tid >> 1, half = tid & 1;
    uint2 t0 = *reinterpret_cast<const uint2*>(&s_tv[d][half * 8]);
    uint2 t1 = *reinterpret_cast<const uint2*>(&s_tv[d][half * 8 + 4]);
    uint4 o; o.x = t0.x; o.y = t0.y; o.z = t1.x; o.w = t1.y;
    *reinterpret_cast<uint4*>(vt + (size_t)d * 8192 + row0 + half * 8) = o;
  }
}

// ---- online softmax for one 16-q half; THR=8 defer-max (exact bookkeeping) ----
__device__ __forceinline__ short8 sm_half(
    const f32x4& s0, const f32x4& s1, float& mrun, float& lrun,
    f32x4* __restrict__ oacc, uint_t* __restrict__ prow, int g)
{
  float t0 = fmaxf(fmaxf(fmaxf(s0[0], s0[1]), fmaxf(s0[2], s0[3])),
                   fmaxf(fmaxf(s1[0], s1[1]), fmaxf(s1[2], s1[3])));
  t0 = fmaxf(t0, __shfl_xor(t0, 16, 64));
  t0 = fmaxf(t0, __shfl_xor(t0, 32, 64));
  // defer-max: rescale only when tile max exceeds running max by >8
  // (exp2 domain -> p bounded by 2^8; l and O stay consistent with mrun)
  if (__any(t0 > mrun + 8.0f)){
    float mnew = fmaxf(mrun, t0);
    float fac  = exp2f(mrun - mnew);
    lrun *= fac;
    #pragma unroll
    for (int dt = 0; dt < 8; ++dt){
      oacc[dt][0] *= fac; oacc[dt][1] *= fac; oacc[dt][2] *= fac; oacc[dt][3] *= fac;
    }
    mrun = mnew;
  }
  float p00 = exp2f(s0[0] - mrun), p01 = exp2f(s0[1] - mrun);
  float p02 = exp2f(s0[2] - mrun), p03 = exp2f(s0[3] - mrun);
  float p10 = exp2f(s1[0] - mrun), p11 = exp2f(s1[1] - mrun);
  float p12 = exp2f(s1[2] - mrun), p13 = exp2f(s1[3] - mrun);
  float ps = ((p00 + p01) + (p02 + p03)) + ((p10 + p11) + (p12 + p13));
  ps += __shfl_xor(ps, 16, 64);
  ps += __shfl_xor(ps, 32, 64);
  lrun += ps;
  uint2 w0; w0.x = cvtpk(p00, p01); w0.y = cvtpk(p02, p03);
  uint2 w1; w1.x = cvtpk(p10, p11); w1.y = cvtpk(p12, p13);
  *reinterpret_cast<uint2*>(prow + 2 * g)     = w0;
  *reinterpret_cast<uint2*>(prow + 8 + 2 * g) = w1;
  return *reinterpret_cast<const short8*>(prow + 4 * g);
}

// ---- MFMA flash attention: 32 q/wave, XOR-swizzled K/V LDS tiles ----
// launch_bounds (256,4): cap 128 VGPR is 1.6x above the ~80 demand -> outside
// the allocator's spilling regime ((256,6) cap 85 spilled to 40: r14).
// reg-prefetch remains BANNED (NaN r11/r12).
template<int NCH_T>
__global__ __launch_bounds__(256, 4) void attn_mfma(
    const ushort_t* __restrict__ qf, const ushort_t* __restrict__ kf, const ushort_t* __restrict__ vt,
    ushort_t* __restrict__ pacc, float* __restrict__ pm, float* __restrict__ pl)
{
  constexpr int CHUNK_T = 8192 / NCH_T;
  constexpr int TILES_T = CHUNK_T / 32;

  const int tid  = threadIdx.x;
  const int lane = tid & 63;
  const int w    = tid >> 6;
  const int g    = lane >> 4;
  const int hl   = lane & 15;
  const int qb   = blockIdx.x & 63;
  const int jc   = blockIdx.x >> 6;
  const int qw   = qb * 128 + w * 32;
  const int qrA  = qw + hl;
  const int qrB  = qw + 16 + hl;

  __shared__ ushort_t s_k[32][128];    // XOR-swizzled: col ^= (row&7)*8
  __shared__ ushort_t s_vt[128][32];   // XOR-swizzled: col ^= (row&3)*8
  __shared__ uint_t   s_p32[4][2][16][20];

  const int kjj0 = tid >> 4;
  const int kkk  = (tid & 15) * 8;
  const int vd0  = tid >> 2;
  const int vjo  = (tid & 3) * 8;
  const int jstart = jc * CHUNK_T;

  short8 qfA[4], qfB[4];
  #pragma unroll
  for (int kt = 0; kt < 4; ++kt){
    qfA[kt] = ld8(qf + (size_t)qrA * 128 + kt * 32 + g * 8);
    qfB[kt] = ld8(qf + (size_t)qrB * 128 + kt * 32 + g * 8);
  }

  f32x4 oA[8], oB[8];
  #pragma unroll
  for (int dt = 0; dt < 8; ++dt){
    oA[dt] = (f32x4){0.f, 0.f, 0.f, 0.f};
    oB[dt] = (f32x4){0.f, 0.f, 0.f, 0.f};
  }
  float mA = -3.0e38f, lA = 0.f, mB = -3.0e38f, lB = 0.f;

  for (int t = 0; t < TILES_T; ++t){
    const int jb = jstart + t * 32;
    __syncthreads();
    #pragma unroll
    for (int i = 0; i < 2; ++i){
      int kr = kjj0 + i * 16;
      *reinterpret_cast<uint4*>(&s_k[kr][kkk ^ ((kr & 7) * 8)]) =
          *reinterpret_cast<const uint4*>(kf + (size_t)(jb + kr) * 128 + kkk);
      int vr = vd0 + i * 64;
      *reinterpret_cast<uint4*>(&s_vt[vr][vjo ^ ((vr & 3) * 8)]) =
          *reinterpret_cast<const uint4*>(vt + (size_t)vr * 8192 + jb + vjo);
    }
    __syncthreads();

    // ---- QK^T for both q-halves; each K fragment read feeds 2 MFMAs ----
    f32x4 sA[2], sB[2];
    #pragma unroll
    for (int jt = 0; jt < 2; ++jt){
      sA[jt] = (f32x4){0.f, 0.f, 0.f, 0.f};
      sB[jt] = (f32x4){0.f, 0.f, 0.f, 0.f};
      #pragma unroll
      for (int kt = 0; kt < 4; ++kt){
        short8 kfr = ld8(&s_k[jt * 16 + hl][(kt * 32 + g * 8) ^ ((hl & 7) * 8)]);
        sA[jt] = __builtin_amdgcn_mfma_f32_16x16x32_bf16(kfr, qfA[kt], sA[jt], 0, 0, 0);
        sB[jt] = __builtin_amdgcn_mfma_f32_16x16x32_bf16(kfr, qfB[kt], sB[jt], 0, 0, 0);
      }
    }

    short8 pfA = sm_half(sA[0], sA[1], mA, lA, oA, &s_p32[w][0][hl][0], g);
    short8 pfB = sm_half(sB[0], sB[1], mB, lB, oB, &s_p32[w][1][hl][0], g);

    // ---- PV for both halves; each V fragment read feeds 2 MFMAs ----
    #pragma unroll
    for (int dt = 0; dt < 8; ++dt){
      short8 vfr = ld8(&s_vt[dt * 16 + hl][(g * 8) ^ ((hl & 3) * 8)]);
      oA[dt] = __builtin_amdgcn_mfma_f32_16x16x32_bf16(vfr, pfA, oA[dt], 0, 0, 0);
      oB[dt] = __builtin_amdgcn_mfma_f32_16x16x32_bf16(vfr, pfB, oB[dt], 0, 0, 0);
    }
  }

  // ---- write partials (bf16, pair-packed 8B stores) ----
  #pragma unroll
  for (int dt = 0; dt < 8; ++dt){
    uint2 a;
    a.x = cvtpk(oA[dt][0], oA[dt][1]);
    a.y = cvtpk(oA[dt][2], oA[dt][3]);
    *reinterpret_cast<uint2*>(pacc + ((size_t)jc * 8192 + qrA) * 128 + dt * 16 + 4 * g) = a;
    uint2 b;
    b.x = cvtpk(oB[dt][0], oB[dt][1]);
    b.y = cvtpk(oB[dt][2], oB[dt][3]);
    *reinterpret_cast<uint2*>(pacc + ((size_t)jc * 8192 + qrB) * 128 + dt * 16 + 4 * g) = b;
  }
  if (g == 0){
    pm[jc * 8192 + qrA] = mA;  pl[jc * 8192 + qrA] = lA;
    pm[jc * 8192 + qrB] = mB;  pl[jc * 8192 + qrB] = lB;
  }
}

// ---- combine chunk partials + residual + halt/stack heads ----
template<int NCH_T>
__global__ __launch_bounds__(256, 1) void combine_kernel(
    const ushort_t* __restrict__ pacc, const float* __restrict__ pm, const float* __restrict__ pl,
    const float* __restrict__ resb,
    const float* __restrict__ halt_W, const float* __restrict__ halt_b,
    const float* __restrict__ stack_W, const float* __restrict__ stack_b,
    float* __restrict__ out)
{
  const int tid  = threadIdx.x;
  const int lane = tid & 63;
  const int w    = tid >> 6;
  const int q    = blockIdx.x * 4 + w;

  float mv[NCH_T], M = -3.0e38f;
  #pragma unroll
  for (int c = 0; c < NCH_T; ++c){ mv[c] = pm[c * 8192 + q]; M = fmaxf(M, mv[c]); }
  float f[NCH_T]; float L = 0.f;
  #pragma unroll
  for (int c = 0; c < NCH_T; ++c){ f[c] = exp2f(mv[c] - M); L += pl[c * 8192 + q] * f[c]; }
  float invL = 1.0f / L;

  float o0 = 0.f, o1 = 0.f;
  #pragma unroll
  for (int c = 0; c < NCH_T; ++c){
    const ushort_t* pa = pacc + ((size_t)c * 8192 + q) * 128;
    o0 += bf2f(pa[lane])      * f[c];
    o1 += bf2f(pa[64 + lane]) * f[c];
  }
  o0 = o0 * invL + resb[(size_t)q * 128 + lane];
  o1 = o1 * invL + resb[(size_t)q * 128 + 64 + lane];
  out[(size_t)q * 64 + lane] = o0;
  out[(size_t)8192 * 64 + (size_t)q * 64 + lane] = o1;

  float ssq  = wave_sum64(o0 * o0 + o1 * o1);
  float invn = 1.0f / (sqrtf(ssq) + 1e-6f);
  float zn0 = o0 * invn, zn1 = o1 * invn;
  float hp = wave_sum64(zn0 * halt_W[lane]        + zn1 * halt_W[64 + lane]);
  float s0 = wave_sum64(zn0 * stack_W[lane]       + zn1 * stack_W[64 + lane]);
  float s1 = wave_sum64(zn0 * stack_W[128 + lane] + zn1 * stack_W[192 + lane]);
  float s2 = wave_sum64(zn0 * stack_W[256 + lane] + zn1 * stack_W[320 + lane]);
  if (lane == 0){
    out[1048576 + q] = hp + halt_b[0];
    out[1056768 + (size_t)q * 3 + 0] = s0 + stack_b[0];
    out[1056768 + (size_t)q * 3 + 1] = s1 + stack_b[1];
    out[1056768 + (size_t)q * 3 + 2] = s2 + stack_b[2];
  }
}

extern "C" void kernel_launch(void* const* d_in, const int* in_sizes, int n_in,
                              void* d_out, int out_size, void* d_ws, size_t ws_size,
                              hipStream_t stream){
  const float* z_real  = (const float*)d_in[0];
  const float* z_imag  = (const float*)d_in[1];
  const float* gate_W  = (const float*)d_in[2];
  const float* gate_b  = (const float*)d_in[3];
  const float* exp_Wr  = (const float*)d_in[4];
  const float* exp_Wi  = (const float*)d_in[5];
  const float* ln_scale= (const float*)d_in[6];
  const float* ln_shift= (const float*)d_in[7];
  const float* mod_bias= (const float*)d_in[8];
  const float* q_Wr    = (const float*)d_in[9];
  const float* q_Wi    = (const float*)d_in[10];
  const float* k_Wr    = (const float*)d_in[11];
  const float* k_Wi    = (const float*)d_in[12];
  const float* v_Wr    = (const float*)d_in[13];
  const float* v_Wi    = (const float*)d_in[14];
  const float* ctx_W   = (const float*)d_in[15];
  const float* ctx_b   = (const float*)d_in[16];
  const float* res_W   = (const float*)d_in[17];
  const float* res_b   = (const float*)d_in[18];
  const float* halt_W  = (const float*)d_in[19];
  const float* halt_b  = (const float*)d_in[20];
  const float* stack_W = (const float*)d_in[21];
  const float* stack_b = (const float*)d_in[22];

  auto need = [&](int nch)->size_t{
    size_t b = (size_t)3 * 8192 * 128 * 2;                       // qbf,kbf,vtb bf16
    b += (size_t)8192 * 128 * 4;                                 // resb fp32
    b += (size_t)nch * 8192 * 128 * 2;                           // pacc bf16
    b += (size_t)2 * nch * 8192 * 4;                             // pm, pl
    b += (size_t)2 * WTOT * 2;                                   // whi, wlo
    return b;
  };
  const int nch = (ws_size >= need(16)) ? 16 : 8;

  ushort_t* qbf = (ushort_t*)d_ws;
  ushort_t* kbf = qbf + (size_t)8192*128;
  ushort_t* vtb = kbf + (size_t)8192*128;
  float* resb = (float*)(vtb + (size_t)8192*128);
  ushort_t* pacc = (ushort_t*)(resb + (size_t)8192*128);
  float* pm   = (float*)(pacc + (size_t)nch*8192*128);
  float* pl   = pm   + (size_t)nch*8192;
  ushort_t* whi = (ushort_t*)(pl + (size_t)nch*8192);
  ushort_t* wlo = whi + WTOT;

  wconv_kernel<<<(WTOT + 255) / 256, 256, 0, stream>>>(gate_W, exp_Wr, exp_Wi,
      q_Wr, q_Wi, k_Wr, k_Wi, v_Wr, v_Wi, ctx_W, res_W, whi, wlo);
  prep_kernel<<<512, 256, 0, stream>>>(z_real, z_imag, whi, wlo, gate_b,
      ln_scale, ln_shift, mod_bias, ctx_b, res_b, qbf, kbf, vtb, resb);
  if (nch == 16){
    attn_mfma<16><<<64*16, 256, 0, stream>>>(qbf, kbf, vtb, pacc, pm, pl);
    combine_kernel<16><<<2048, 256, 0, stream>>>(pacc, pm, pl, resb,
        halt_W, halt_b, stack_W, stack_b, (float*)d_out);
  } else {
    attn_mfma<8><<<64*8, 256, 0, stream>>>(qbf, kbf, vtb, pacc, pm, pl);
    combine_kernel<8><<<2048, 256, 0, stream>>>(pacc, pm, pl, resb,
        halt_W, halt_b, stack_W, stack_b, (float*)d_out);
  }
}

// Round 17
// 109.249 us; speedup vs baseline: 4.1920x; 1.1992x over previous
//
#include <hip/hip_runtime.h>
#include <math.h>

#define EPS_F 1e-6f
#define QSC   (0.125f * 1.44269504088896340736f)   // ATTN_SCALE * log2(e)

// weight-buffer offsets (elements) in whi/wlo
#define GATE_O 0
#define EWR_O  512
#define EWI_O  16896
#define QWR_O  33280
#define QWI_O  37376
#define KWR_O  41472
#define KWI_O  45568
#define VWR_O  49664
#define VWI_O  53760
#define CTX_O  57856
#define RES_O  74240
#define WTOT   90624

typedef __attribute__((ext_vector_type(8))) short short8;
typedef __attribute__((ext_vector_type(4))) float f32x4;
typedef unsigned short ushort_t;
typedef unsigned int uint_t;

__device__ __forceinline__ ushort_t f2bf(float x){
  uint_t u = __float_as_uint(x);
  u += 0x7fffu + ((u >> 16) & 1u);
  return (ushort_t)(u >> 16);
}
__device__ __forceinline__ float bf2f(ushort_t u){
  return __uint_as_float(((uint_t)u) << 16);
}
// hardware packed f32->bf16 (RNE), 1 inst for 2 values
__device__ __forceinline__ uint_t cvtpk(float lo, float hi){
  uint_t r;
  asm("v_cvt_pk_bf16_f32 %0, %1, %2" : "=v"(r) : "v"(lo), "v"(hi));
  return r;
}

__device__ __forceinline__ float wave_sum64(float v){
  #pragma unroll
  for (int m = 32; m > 0; m >>= 1) v += __shfl_xor(v, m, 64);
  return v;
}
__device__ __forceinline__ float qsum16(float v){
  #pragma unroll
  for (int m = 1; m < 16; m <<= 1) v += __shfl_xor(v, m, 64);
  return v;
}

__device__ __forceinline__ short8 neg8(short8 v){
  uint4 u = *reinterpret_cast<uint4*>(&v);
  u.x ^= 0x80008000u; u.y ^= 0x80008000u; u.z ^= 0x80008000u; u.w ^= 0x80008000u;
  return *reinterpret_cast<short8*>(&u);
}
__device__ __forceinline__ short8 ld8(const ushort_t* __restrict__ p){
  return *reinterpret_cast<const short8*>(p);
}

#define MFMA(a,b,c) __builtin_amdgcn_mfma_f32_16x16x32_bf16((a),(b),(c),0,0,0)

// ============ weight conversion: fp32 -> bf16 hi/lo, fragment-ready ============
__global__ __launch_bounds__(256) void wconv_kernel(
    const float* __restrict__ gate_W, const float* __restrict__ exp_Wr,
    const float* __restrict__ exp_Wi,
    const float* __restrict__ q_Wr, const float* __restrict__ q_Wi,
    const float* __restrict__ k_Wr, const float* __restrict__ k_Wi,
    const float* __restrict__ v_Wr, const float* __restrict__ v_Wi,
    const float* __restrict__ ctx_W, const float* __restrict__ res_W,
    ushort_t* __restrict__ whi, ushort_t* __restrict__ wlo)
{
  int i = blockIdx.x * 256 + threadIdx.x;
  if (i >= WTOT) return;
  float v;
  if      (i < EWR_O) v = gate_W[i - GATE_O];
  else if (i < EWI_O) v = exp_Wr[i - EWR_O];
  else if (i < QWR_O) v = exp_Wi[i - EWI_O];
  else if (i < QWI_O) v = q_Wr[i - QWR_O];
  else if (i < KWR_O) v = q_Wi[i - QWI_O];
  else if (i < KWI_O) v = k_Wr[i - KWR_O];
  else if (i < VWR_O) v = k_Wi[i - KWI_O];
  else if (i < VWI_O) v = v_Wr[i - VWR_O];
  else if (i < CTX_O) v = v_Wi[i - VWI_O];
  else if (i < RES_O) v = ctx_W[i - CTX_O];
  else                v = res_W[i - RES_O];
  ushort_t h = f2bf(v);
  whi[i] = h;
  wlo[i] = f2bf(v - bf2f(h));
}

// ============ prep v3: MFMA everywhere, 4 waves/block, wave = col-tile ============
__global__ __launch_bounds__(256, 4) void prep_kernel(
    const float* __restrict__ z_real, const float* __restrict__ z_imag,
    const ushort_t* __restrict__ whi, const ushort_t* __restrict__ wlo,
    const float* __restrict__ gate_b,
    const float* __restrict__ ln_scale, const float* __restrict__ ln_shift,
    const float* __restrict__ mod_bias,
    const float* __restrict__ ctx_b, const float* __restrict__ res_b,
    ushort_t* __restrict__ qf, ushort_t* __restrict__ kf, ushort_t* __restrict__ vt,
    float* __restrict__ resb)
{
  const int tid  = threadIdx.x;
  const int lane = tid & 63;
  const int w    = tid >> 6;
  const int g    = lane >> 4;
  const int c    = lane & 15;
  const int row0 = blockIdx.x * 16;
  const int col  = w * 16 + c;
  const f32x4 z4 = {0.f, 0.f, 0.f, 0.f};

  __shared__ ushort_t s_xh[16][136];
  __shared__ ushort_t s_xl[16][136];
  __shared__ ushort_t s_a [16][136];
  __shared__ ushort_t s_tv[128][20];
  __shared__ float    s_red[4][16][2];

  {
    int rowl = tid >> 4;
    int col0 = (tid & 15) * 8;
    const float* src = (col0 < 64) ? (z_real + (size_t)(row0 + rowl) * 64 + col0)
                                   : (z_imag + (size_t)(row0 + rowl) * 64 + (col0 - 64));
    float4 a = *reinterpret_cast<const float4*>(src);
    float4 b = *reinterpret_cast<const float4*>(src + 4);
    float f[8] = {a.x, a.y, a.z, a.w, b.x, b.y, b.z, b.w};
    uint_t hp[4], lp[4];
    #pragma unroll
    for (int e = 0; e < 4; ++e){
      ushort_t h0 = f2bf(f[2*e]), h1 = f2bf(f[2*e+1]);
      hp[e] = (uint_t)h0 | ((uint_t)h1 << 16);
      lp[e] = (uint_t)f2bf(f[2*e]   - bf2f(h0)) |
              ((uint_t)f2bf(f[2*e+1] - bf2f(h1)) << 16);
    }
    uint4 uh; uh.x = hp[0]; uh.y = hp[1]; uh.z = hp[2]; uh.w = hp[3];
    uint4 ul; ul.x = lp[0]; ul.y = lp[1]; ul.z = lp[2]; ul.w = lp[3];
    *reinterpret_cast<uint4*>(&s_xh[rowl][col0]) = uh;
    *reinterpret_cast<uint4*>(&s_xl[rowl][col0]) = ul;
  }
  __syncthreads();

  short8 xh[4], xl[4];
  #pragma unroll
  for (int ks = 0; ks < 4; ++ks){
    xh[ks] = ld8(&s_xh[c][ks * 32 + g * 8]);
    xl[ks] = ld8(&s_xl[c][ks * 32 + g * 8]);
  }

  // ---- gate (compensated) ----
  float gwv[4];
  {
    f32x4 ga = z4;
    #pragma unroll
    for (int ks = 0; ks < 4; ++ks){
      int off = GATE_O + (c & 3) * 128 + ks * 32 + g * 8;
      short8 wh = ld8(whi + off), wl = ld8(wlo + off);
      ga = MFMA(xh[ks], wh, ga);
      ga = MFMA(xl[ks], wh, ga);
      ga = MFMA(xh[ks], wl, ga);
    }
    float gb = gate_b[c & 3];
    #pragma unroll
    for (int r = 0; r < 4; ++r){
      float le = ga[r] + gb;
      float mx = fmaxf(le, __shfl_xor(le, 1, 64));
      mx = fmaxf(mx, __shfl_xor(mx, 2, 64));
      float ev = __expf(le - mx);
      float sm = ev + __shfl_xor(ev, 1, 64);
      sm += __shfl_xor(sm, 2, 64);
      gwv[r] = ev / sm;
    }
  }

  // ---- MoE (compensated) ----
  f32x4 mrr = z4, mri = z4;
  #pragma unroll
  for (int e = 0; e < 4; ++e){
    float gwr[4];
    #pragma unroll
    for (int r = 0; r < 4; ++r) gwr[r] = __shfl(gwv[r], g * 16 + e, 64);
    f32x4 er = z4, ei = z4;
    #pragma unroll
    for (int ks = 0; ks < 2; ++ks){
      int boff = e * 4096 + col * 64 + ks * 32 + g * 8;
      short8 wrh = ld8(whi + EWR_O + boff);
      short8 wrl = ld8(wlo + EWR_O + boff);
      short8 wih = ld8(whi + EWI_O + boff);
      short8 wil = ld8(wlo + EWI_O + boff);
      short8 wihn = neg8(wih), wiln = neg8(wil);
      er = MFMA(xh[ks],   wrh, er);   ei = MFMA(xh[ks+2], wrh, ei);
      er = MFMA(xl[ks],   wrh, er);   ei = MFMA(xl[ks+2], wrh, ei);
      er = MFMA(xh[ks],   wrl, er);   ei = MFMA(xh[ks+2], wrl, ei);
      er = MFMA(xh[ks+2], wihn, er);  ei = MFMA(xh[ks],   wih, ei);
      er = MFMA(xl[ks+2], wihn, er);  ei = MFMA(xl[ks],   wih, ei);
      er = MFMA(xh[ks+2], wiln, er);  ei = MFMA(xh[ks],   wil, ei);
    }
    #pragma unroll
    for (int r = 0; r < 4; ++r){
      mrr[r] = fmaf(gwr[r], er[r], mrr[r]);
      mri[r] = fmaf(gwr[r], ei[r], mri[r]);
    }
  }

  // ---- ComplexLayerNorm (ddof=1) + ModReLU ----
  {
    float hh[4], mg[4];
    #pragma unroll
    for (int r = 0; r < 4; ++r){
      hh[r] = sqrtf(mrr[r] * mrr[r] + mri[r] * mri[r]);
      mg[r] = hh[r] + EPS_F;
    }
    #pragma unroll
    for (int r = 0; r < 4; ++r){
      float sx  = qsum16(mg[r]);
      float sxx = qsum16(mg[r] * mg[r]);
      if (c == 0){ s_red[w][g * 4 + r][0] = sx; s_red[w][g * 4 + r][1] = sxx; }
    }
    __syncthreads();
    float lsc = ln_scale[col], lsh = ln_shift[col], mb = mod_bias[col];
    #pragma unroll
    for (int r = 0; r < 4; ++r){
      int rr = g * 4 + r;
      float SX  = s_red[0][rr][0] + s_red[1][rr][0] + s_red[2][rr][0] + s_red[3][rr][0];
      float SXX = s_red[0][rr][1] + s_red[1][rr][1] + s_red[2][rr][1] + s_red[3][rr][1];
      float mean = SX * (1.0f / 64.0f);
      float var  = (SXX - SX * mean) * (1.0f / 63.0f);
      float istd = rsqrtf(var + EPS_F);
      float nm = (mg[r] - mean) * istd * lsc + lsh;
      float lr, li;
      if (hh[r] > 0.f){ float ih = 1.0f / hh[r]; lr = nm * mrr[r] * ih; li = nm * mri[r] * ih; }
      else            { lr = nm; li = 0.f; }
      float nrm = sqrtf(lr * lr + li * li) + EPS_F;
      float sf  = fmaxf(nrm + mb, 0.f) / nrm;
      s_a[rr][col]      = f2bf(lr * sf);
      s_a[rr][64 + col] = f2bf(li * sf);
    }
  }
  __syncthreads();

  // ---- ctx gate ----
  f32x4 cwa[2];
  #pragma unroll
  for (int ii = 0; ii < 2; ++ii){
    int ct8 = w + ii * 4;
    f32x4 a = z4;
    #pragma unroll
    for (int ks = 0; ks < 4; ++ks)
      a = MFMA(xh[ks], ld8(whi + CTX_O + (ct8 * 16 + c) * 128 + ks * 32 + g * 8), a);
    float cb = ctx_b[ct8 * 16 + c];
    #pragma unroll
    for (int r = 0; r < 4; ++r) cwa[ii][r] = 1.0f / (1.0f + __expf(-(a[r] + cb)));
  }

  // ---- residual ----
  #pragma unroll
  for (int ii = 0; ii < 2; ++ii){
    int ct8 = w + ii * 4;
    f32x4 a = z4;
    #pragma unroll
    for (int ks = 0; ks < 4; ++ks)
      a = MFMA(xh[ks], ld8(whi + RES_O + (ct8 * 16 + c) * 128 + ks * 32 + g * 8), a);
    float rb = res_b[ct8 * 16 + c];
    #pragma unroll
    for (int r = 0; r < 4; ++r)
      resb[(size_t)(row0 + 4 * g + r) * 128 + ct8 * 16 + c] = 0.1f * (a[r] + rb);
  }

  // ---- QKV ----
  short8 ar_[2], ai_[2], ain_[2];
  #pragma unroll
  for (int ks = 0; ks < 2; ++ks){
    ar_[ks]  = ld8(&s_a[c][ks * 32 + g * 8]);
    ai_[ks]  = ld8(&s_a[c][64 + ks * 32 + g * 8]);
    ain_[ks] = neg8(ai_[ks]);
  }

  #pragma unroll
  for (int mat = 0; mat < 3; ++mat){
    int roff = (mat == 0) ? QWR_O : (mat == 1) ? KWR_O : VWR_O;
    int ioff = (mat == 0) ? QWI_O : (mat == 1) ? KWI_O : VWI_O;
    f32x4 orr = z4, oii = z4;
    #pragma unroll
    for (int ks = 0; ks < 2; ++ks){
      int boff = col * 64 + ks * 32 + g * 8;
      short8 wrh = ld8(whi + roff + boff);
      short8 wrl = ld8(wlo + roff + boff);
      short8 wih = ld8(whi + ioff + boff);
      short8 wil = ld8(wlo + ioff + boff);
      orr = MFMA(ar_[ks],  wrh, orr);  oii = MFMA(ai_[ks], wrh, oii);
      orr = MFMA(ar_[ks],  wrl, orr);  oii = MFMA(ai_[ks], wrl, oii);
      orr = MFMA(ain_[ks], wih, orr);  oii = MFMA(ar_[ks], wih, oii);
      orr = MFMA(ain_[ks], wil, orr);  oii = MFMA(ar_[ks], wil, oii);
    }
    if (mat == 0){
      #pragma unroll
      for (int r = 0; r < 4; ++r){
        size_t row = row0 + 4 * g + r;
        qf[row * 128 + col]      = f2bf(orr[r] * cwa[0][r] * QSC);
        qf[row * 128 + 64 + col] = f2bf(oii[r] * cwa[1][r] * QSC);
      }
    } else if (mat == 1){
      #pragma unroll
      for (int r = 0; r < 4; ++r){
        size_t row = row0 + 4 * g + r;
        kf[row * 128 + col]      = f2bf(orr[r]);
        kf[row * 128 + 64 + col] = f2bf(oii[r]);
      }
    } else {
      #pragma unroll
      for (int r = 0; r < 4; ++r){
        s_tv[col][4 * g + r]      = f2bf(orr[r]);
        s_tv[64 + col][4 * g + r] = f2bf(oii[r]);
      }
    }
  }
  __syncthreads();

  {
    int d = tid >> 1, half = tid & 1;
    uint2 t0 = *reinterpret_cast<const uint2*>(&s_tv[d][half * 8]);
    uint2 t1 = *reinterpret_cast<const uint2*>(&s_tv[d][half * 8 + 4]);
    uint4 o; o.x = t0.x; o.y = t0.y; o.z = t1.x; o.w = t1.y;
    *reinterpret_cast<uint4*>(vt + (size_t)d * 8192 + row0 + half * 8) = o;
  }
}

// ---- online softmax for one 16-q half; THR=8 defer-max (exact bookkeeping) ----
__device__ __forceinline__ short8 sm_half(
    const f32x4& s0, const f32x4& s1, float& mrun, float& lrun,
    f32x4* __restrict__ oacc, uint_t* __restrict__ prow, int g)
{
  float t0 = fmaxf(fmaxf(fmaxf(s0[0], s0[1]), fmaxf(s0[2], s0[3])),
                   fmaxf(fmaxf(s1[0], s1[1]), fmaxf(s1[2], s1[3])));
  t0 = fmaxf(t0, __shfl_xor(t0, 16, 64));
  t0 = fmaxf(t0, __shfl_xor(t0, 32, 64));
  // defer-max: rescale only when tile max exceeds running max by >8
  // (exp2 domain -> p bounded by 2^8; l and O stay consistent with mrun)
  if (__any(t0 > mrun + 8.0f)){
    float mnew = fmaxf(mrun, t0);
    float fac  = exp2f(mrun - mnew);
    lrun *= fac;
    #pragma unroll
    for (int dt = 0; dt < 8; ++dt){
      oacc[dt][0] *= fac; oacc[dt][1] *= fac; oacc[dt][2] *= fac; oacc[dt][3] *= fac;
    }
    mrun = mnew;
  }
  float p00 = exp2f(s0[0] - mrun), p01 = exp2f(s0[1] - mrun);
  float p02 = exp2f(s0[2] - mrun), p03 = exp2f(s0[3] - mrun);
  float p10 = exp2f(s1[0] - mrun), p11 = exp2f(s1[1] - mrun);
  float p12 = exp2f(s1[2] - mrun), p13 = exp2f(s1[3] - mrun);
  float ps = ((p00 + p01) + (p02 + p03)) + ((p10 + p11) + (p12 + p13));
  ps += __shfl_xor(ps, 16, 64);
  ps += __shfl_xor(ps, 32, 64);
  lrun += ps;
  uint2 w0; w0.x = cvtpk(p00, p01); w0.y = cvtpk(p02, p03);
  uint2 w1; w1.x = cvtpk(p10, p11); w1.y = cvtpk(p12, p13);
  *reinterpret_cast<uint2*>(prow + 2 * g)     = w0;
  *reinterpret_cast<uint2*>(prow + 8 + 2 * g) = w1;
  return *reinterpret_cast<const short8*>(prow + 4 * g);
}

// ---- MFMA flash attention: 32 q/wave, XOR-swizzled K/V LDS tiles ----
// Round-13-proven structure (2 barriers/tile, stage-then-compute).
// BANNED (NaN): reg-prefetch (r11/r12), LDS double-buffer (r16).
// BANNED (spill): launch_bounds waves/EU 4/6 (r14/r15); (256,3) is stable.
template<int NCH_T>
__global__ __launch_bounds__(256, 3) void attn_mfma(
    const ushort_t* __restrict__ qf, const ushort_t* __restrict__ kf, const ushort_t* __restrict__ vt,
    ushort_t* __restrict__ pacc, float* __restrict__ pm, float* __restrict__ pl)
{
  constexpr int CHUNK_T = 8192 / NCH_T;
  constexpr int TILES_T = CHUNK_T / 32;

  const int tid  = threadIdx.x;
  const int lane = tid & 63;
  const int w    = tid >> 6;
  const int g    = lane >> 4;
  const int hl   = lane & 15;
  const int qb   = blockIdx.x & 63;
  const int jc   = blockIdx.x >> 6;
  const int qw   = qb * 128 + w * 32;
  const int qrA  = qw + hl;
  const int qrB  = qw + 16 + hl;

  __shared__ ushort_t s_k[32][128];    // XOR-swizzled: col ^= (row&7)*8
  __shared__ ushort_t s_vt[128][32];   // XOR-swizzled: col ^= (row&3)*8
  __shared__ uint_t   s_p32[4][2][16][20];

  const int kjj0 = tid >> 4;
  const int kkk  = (tid & 15) * 8;
  const int vd0  = tid >> 2;
  const int vjo  = (tid & 3) * 8;
  const int jstart = jc * CHUNK_T;

  short8 qfA[4], qfB[4];
  #pragma unroll
  for (int kt = 0; kt < 4; ++kt){
    qfA[kt] = ld8(qf + (size_t)qrA * 128 + kt * 32 + g * 8);
    qfB[kt] = ld8(qf + (size_t)qrB * 128 + kt * 32 + g * 8);
  }

  f32x4 oA[8], oB[8];
  #pragma unroll
  for (int dt = 0; dt < 8; ++dt){
    oA[dt] = (f32x4){0.f, 0.f, 0.f, 0.f};
    oB[dt] = (f32x4){0.f, 0.f, 0.f, 0.f};
  }
  float mA = -3.0e38f, lA = 0.f, mB = -3.0e38f, lB = 0.f;

  for (int t = 0; t < TILES_T; ++t){
    const int jb = jstart + t * 32;
    __syncthreads();
    #pragma unroll
    for (int i = 0; i < 2; ++i){
      int kr = kjj0 + i * 16;
      *reinterpret_cast<uint4*>(&s_k[kr][kkk ^ ((kr & 7) * 8)]) =
          *reinterpret_cast<const uint4*>(kf + (size_t)(jb + kr) * 128 + kkk);
      int vr = vd0 + i * 64;
      *reinterpret_cast<uint4*>(&s_vt[vr][vjo ^ ((vr & 3) * 8)]) =
          *reinterpret_cast<const uint4*>(vt + (size_t)vr * 8192 + jb + vjo);
    }
    __syncthreads();

    // ---- QK^T for both q-halves; each K fragment read feeds 2 MFMAs ----
    f32x4 sA[2], sB[2];
    #pragma unroll
    for (int jt = 0; jt < 2; ++jt){
      sA[jt] = (f32x4){0.f, 0.f, 0.f, 0.f};
      sB[jt] = (f32x4){0.f, 0.f, 0.f, 0.f};
      #pragma unroll
      for (int kt = 0; kt < 4; ++kt){
        short8 kfr = ld8(&s_k[jt * 16 + hl][(kt * 32 + g * 8) ^ ((hl & 7) * 8)]);
        sA[jt] = __builtin_amdgcn_mfma_f32_16x16x32_bf16(kfr, qfA[kt], sA[jt], 0, 0, 0);
        sB[jt] = __builtin_amdgcn_mfma_f32_16x16x32_bf16(kfr, qfB[kt], sB[jt], 0, 0, 0);
      }
    }

    short8 pfA = sm_half(sA[0], sA[1], mA, lA, oA, &s_p32[w][0][hl][0], g);
    short8 pfB = sm_half(sB[0], sB[1], mB, lB, oB, &s_p32[w][1][hl][0], g);

    // ---- PV for both halves; each V fragment read feeds 2 MFMAs ----
    #pragma unroll
    for (int dt = 0; dt < 8; ++dt){
      short8 vfr = ld8(&s_vt[dt * 16 + hl][(g * 8) ^ ((hl & 3) * 8)]);
      oA[dt] = __builtin_amdgcn_mfma_f32_16x16x32_bf16(vfr, pfA, oA[dt], 0, 0, 0);
      oB[dt] = __builtin_amdgcn_mfma_f32_16x16x32_bf16(vfr, pfB, oB[dt], 0, 0, 0);
    }
  }

  // ---- write partials (bf16, pair-packed 8B stores) ----
  #pragma unroll
  for (int dt = 0; dt < 8; ++dt){
    uint2 a;
    a.x = cvtpk(oA[dt][0], oA[dt][1]);
    a.y = cvtpk(oA[dt][2], oA[dt][3]);
    *reinterpret_cast<uint2*>(pacc + ((size_t)jc * 8192 + qrA) * 128 + dt * 16 + 4 * g) = a;
    uint2 b;
    b.x = cvtpk(oB[dt][0], oB[dt][1]);
    b.y = cvtpk(oB[dt][2], oB[dt][3]);
    *reinterpret_cast<uint2*>(pacc + ((size_t)jc * 8192 + qrB) * 128 + dt * 16 + 4 * g) = b;
  }
  if (g == 0){
    pm[jc * 8192 + qrA] = mA;  pl[jc * 8192 + qrA] = lA;
    pm[jc * 8192 + qrB] = mB;  pl[jc * 8192 + qrB] = lB;
  }
}

// ---- combine chunk partials + residual + halt/stack heads ----
template<int NCH_T>
__global__ __launch_bounds__(256, 1) void combine_kernel(
    const ushort_t* __restrict__ pacc, const float* __restrict__ pm, const float* __restrict__ pl,
    const float* __restrict__ resb,
    const float* __restrict__ halt_W, const float* __restrict__ halt_b,
    const float* __restrict__ stack_W, const float* __restrict__ stack_b,
    float* __restrict__ out)
{
  const int tid  = threadIdx.x;
  const int lane = tid & 63;
  const int w    = tid >> 6;
  const int q    = blockIdx.x * 4 + w;

  float mv[NCH_T], M = -3.0e38f;
  #pragma unroll
  for (int c = 0; c < NCH_T; ++c){ mv[c] = pm[c * 8192 + q]; M = fmaxf(M, mv[c]); }
  float f[NCH_T]; float L = 0.f;
  #pragma unroll
  for (int c = 0; c < NCH_T; ++c){ f[c] = exp2f(mv[c] - M); L += pl[c * 8192 + q] * f[c]; }
  float invL = 1.0f / L;

  float o0 = 0.f, o1 = 0.f;
  #pragma unroll
  for (int c = 0; c < NCH_T; ++c){
    const ushort_t* pa = pacc + ((size_t)c * 8192 + q) * 128;
    o0 += bf2f(pa[lane])      * f[c];
    o1 += bf2f(pa[64 + lane]) * f[c];
  }
  o0 = o0 * invL + resb[(size_t)q * 128 + lane];
  o1 = o1 * invL + resb[(size_t)q * 128 + 64 + lane];
  out[(size_t)q * 64 + lane] = o0;
  out[(size_t)8192 * 64 + (size_t)q * 64 + lane] = o1;

  float ssq  = wave_sum64(o0 * o0 + o1 * o1);
  float invn = 1.0f / (sqrtf(ssq) + 1e-6f);
  float zn0 = o0 * invn, zn1 = o1 * invn;
  float hp = wave_sum64(zn0 * halt_W[lane]        + zn1 * halt_W[64 + lane]);
  float s0 = wave_sum64(zn0 * stack_W[lane]       + zn1 * stack_W[64 + lane]);
  float s1 = wave_sum64(zn0 * stack_W[128 + lane] + zn1 * stack_W[192 + lane]);
  float s2 = wave_sum64(zn0 * stack_W[256 + lane] + zn1 * stack_W[320 + lane]);
  if (lane == 0){
    out[1048576 + q] = hp + halt_b[0];
    out[1056768 + (size_t)q * 3 + 0] = s0 + stack_b[0];
    out[1056768 + (size_t)q * 3 + 1] = s1 + stack_b[1];
    out[1056768 + (size_t)q * 3 + 2] = s2 + stack_b[2];
  }
}

extern "C" void kernel_launch(void* const* d_in, const int* in_sizes, int n_in,
                              void* d_out, int out_size, void* d_ws, size_t ws_size,
                              hipStream_t stream){
  const float* z_real  = (const float*)d_in[0];
  const float* z_imag  = (const float*)d_in[1];
  const float* gate_W  = (const float*)d_in[2];
  const float* gate_b  = (const float*)d_in[3];
  const float* exp_Wr  = (const float*)d_in[4];
  const float* exp_Wi  = (const float*)d_in[5];
  const float* ln_scale= (const float*)d_in[6];
  const float* ln_shift= (const float*)d_in[7];
  const float* mod_bias= (const float*)d_in[8];
  const float* q_Wr    = (const float*)d_in[9];
  const float* q_Wi    = (const float*)d_in[10];
  const float* k_Wr    = (const float*)d_in[11];
  const float* k_Wi    = (const float*)d_in[12];
  const float* v_Wr    = (const float*)d_in[13];
  const float* v_Wi    = (const float*)d_in[14];
  const float* ctx_W   = (const float*)d_in[15];
  const float* ctx_b   = (const float*)d_in[16];
  const float* res_W   = (const float*)d_in[17];
  const float* res_b   = (const float*)d_in[18];
  const float* halt_W  = (const float*)d_in[19];
  const float* halt_b  = (const float*)d_in[20];
  const float* stack_W = (const float*)d_in[21];
  const float* stack_b = (const float*)d_in[22];

  auto need = [&](int nch)->size_t{
    size_t b = (size_t)3 * 8192 * 128 * 2;                       // qbf,kbf,vtb bf16
    b += (size_t)8192 * 128 * 4;                                 // resb fp32
    b += (size_t)nch * 8192 * 128 * 2;                           // pacc bf16
    b += (size_t)2 * nch * 8192 * 4;                             // pm, pl
    b += (size_t)2 * WTOT * 2;                                   // whi, wlo
    return b;
  };
  const int nch = (ws_size >= need(16)) ? 16 : 8;

  ushort_t* qbf = (ushort_t*)d_ws;
  ushort_t* kbf = qbf + (size_t)8192*128;
  ushort_t* vtb = kbf + (size_t)8192*128;
  float* resb = (float*)(vtb + (size_t)8192*128);
  ushort_t* pacc = (ushort_t*)(resb + (size_t)8192*128);
  float* pm   = (float*)(pacc + (size_t)nch*8192*128);
  float* pl   = pm   + (size_t)nch*8192;
  ushort_t* whi = (ushort_t*)(pl + (size_t)nch*8192);
  ushort_t* wlo = whi + WTOT;

  wconv_kernel<<<(WTOT + 255) / 256, 256, 0, stream>>>(gate_W, exp_Wr, exp_Wi,
      q_Wr, q_Wi, k_Wr, k_Wi, v_Wr, v_Wi, ctx_W, res_W, whi, wlo);
  prep_kernel<<<512, 256, 0, stream>>>(z_real, z_imag, whi, wlo, gate_b,
      ln_scale, ln_shift, mod_bias, ctx_b, res_b, qbf, kbf, vtb, resb);
  if (nch == 16){
    attn_mfma<16><<<64*16, 256, 0, stream>>>(qbf, kbf, vtb, pacc, pm, pl);
    combine_kernel<16><<<2048, 256, 0, stream>>>(pacc, pm, pl, resb,
        halt_W, halt_b, stack_W, stack_b, (float*)d_out);
  } else {
    attn_mfma<8><<<64*8, 256, 0, stream>>>(qbf, kbf, vtb, pacc, pm, pl);
    combine_kernel<8><<<2048, 256, 0, stream>>>(pacc, pm, pl, resb,
        halt_W, halt_b, stack_W, stack_b, (float*)d_out);
  }
}

// Round 18
// 104.720 us; speedup vs baseline: 4.3732x; 1.0432x over previous
//
#include <hip/hip_runtime.h>
#include <math.h>

#define EPS_F 1e-6f
#define QSC   (0.125f * 1.44269504088896340736f)   // ATTN_SCALE * log2(e)

// weight-buffer offsets (elements) in whi/wlo
#define GATE_O 0
#define EWR_O  512
#define EWI_O  16896
#define QWR_O  33280
#define QWI_O  37376
#define KWR_O  41472
#define KWI_O  45568
#define VWR_O  49664
#define VWI_O  53760
#define CTX_O  57856
#define RES_O  74240
#define WTOT   90624

typedef __attribute__((ext_vector_type(8))) short short8;
typedef __attribute__((ext_vector_type(4))) float f32x4;
typedef unsigned short ushort_t;
typedef unsigned int uint_t;

__device__ __forceinline__ ushort_t f2bf(float x){
  uint_t u = __float_as_uint(x);
  u += 0x7fffu + ((u >> 16) & 1u);
  return (ushort_t)(u >> 16);
}
__device__ __forceinline__ float bf2f(ushort_t u){
  return __uint_as_float(((uint_t)u) << 16);
}
// hardware packed f32->bf16 (RNE), 1 inst for 2 values
__device__ __forceinline__ uint_t cvtpk(float lo, float hi){
  uint_t r;
  asm("v_cvt_pk_bf16_f32 %0, %1, %2" : "=v"(r) : "v"(lo), "v"(hi));
  return r;
}

__device__ __forceinline__ float wave_sum64(float v){
  #pragma unroll
  for (int m = 32; m > 0; m >>= 1) v += __shfl_xor(v, m, 64);
  return v;
}
__device__ __forceinline__ float qsum16(float v){
  #pragma unroll
  for (int m = 1; m < 16; m <<= 1) v += __shfl_xor(v, m, 64);
  return v;
}

__device__ __forceinline__ short8 neg8(short8 v){
  uint4 u = *reinterpret_cast<uint4*>(&v);
  u.x ^= 0x80008000u; u.y ^= 0x80008000u; u.z ^= 0x80008000u; u.w ^= 0x80008000u;
  return *reinterpret_cast<short8*>(&u);
}
__device__ __forceinline__ short8 ld8(const ushort_t* __restrict__ p){
  return *reinterpret_cast<const short8*>(p);
}

#define MFMA(a,b,c) __builtin_amdgcn_mfma_f32_16x16x32_bf16((a),(b),(c),0,0,0)

// ============ weight conversion: fp32 -> bf16 hi/lo, fragment-ready ============
__global__ __launch_bounds__(256) void wconv_kernel(
    const float* __restrict__ gate_W, const float* __restrict__ exp_Wr,
    const float* __restrict__ exp_Wi,
    const float* __restrict__ q_Wr, const float* __restrict__ q_Wi,
    const float* __restrict__ k_Wr, const float* __restrict__ k_Wi,
    const float* __restrict__ v_Wr, const float* __restrict__ v_Wi,
    const float* __restrict__ ctx_W, const float* __restrict__ res_W,
    ushort_t* __restrict__ whi, ushort_t* __restrict__ wlo)
{
  int i = blockIdx.x * 256 + threadIdx.x;
  if (i >= WTOT) return;
  float v;
  if      (i < EWR_O) v = gate_W[i - GATE_O];
  else if (i < EWI_O) v = exp_Wr[i - EWR_O];
  else if (i < QWR_O) v = exp_Wi[i - EWI_O];
  else if (i < QWI_O) v = q_Wr[i - QWR_O];
  else if (i < KWR_O) v = q_Wi[i - QWI_O];
  else if (i < KWI_O) v = k_Wr[i - KWR_O];
  else if (i < VWR_O) v = k_Wi[i - KWI_O];
  else if (i < VWI_O) v = v_Wr[i - VWR_O];
  else if (i < CTX_O) v = v_Wi[i - VWI_O];
  else if (i < RES_O) v = ctx_W[i - CTX_O];
  else                v = res_W[i - RES_O];
  ushort_t h = f2bf(v);
  whi[i] = h;
  wlo[i] = f2bf(v - bf2f(h));
}

// ============ prep v3: MFMA everywhere, 4 waves/block, wave = col-tile ============
__global__ __launch_bounds__(256, 4) void prep_kernel(
    const float* __restrict__ z_real, const float* __restrict__ z_imag,
    const ushort_t* __restrict__ whi, const ushort_t* __restrict__ wlo,
    const float* __restrict__ gate_b,
    const float* __restrict__ ln_scale, const float* __restrict__ ln_shift,
    const float* __restrict__ mod_bias,
    const float* __restrict__ ctx_b, const float* __restrict__ res_b,
    ushort_t* __restrict__ qf, ushort_t* __restrict__ kf, ushort_t* __restrict__ vt,
    float* __restrict__ resb)
{
  const int tid  = threadIdx.x;
  const int lane = tid & 63;
  const int w    = tid >> 6;
  const int g    = lane >> 4;
  const int c    = lane & 15;
  const int row0 = blockIdx.x * 16;
  const int col  = w * 16 + c;
  const f32x4 z4 = {0.f, 0.f, 0.f, 0.f};

  __shared__ ushort_t s_xh[16][136];
  __shared__ ushort_t s_xl[16][136];
  __shared__ ushort_t s_a [16][136];
  __shared__ ushort_t s_tv[128][20];
  __shared__ float    s_red[4][16][2];

  {
    int rowl = tid >> 4;
    int col0 = (tid & 15) * 8;
    const float* src = (col0 < 64) ? (z_real + (size_t)(row0 + rowl) * 64 + col0)
                                   : (z_imag + (size_t)(row0 + rowl) * 64 + (col0 - 64));
    float4 a = *reinterpret_cast<const float4*>(src);
    float4 b = *reinterpret_cast<const float4*>(src + 4);
    float f[8] = {a.x, a.y, a.z, a.w, b.x, b.y, b.z, b.w};
    uint_t hp[4], lp[4];
    #pragma unroll
    for (int e = 0; e < 4; ++e){
      ushort_t h0 = f2bf(f[2*e]), h1 = f2bf(f[2*e+1]);
      hp[e] = (uint_t)h0 | ((uint_t)h1 << 16);
      lp[e] = (uint_t)f2bf(f[2*e]   - bf2f(h0)) |
              ((uint_t)f2bf(f[2*e+1] - bf2f(h1)) << 16);
    }
    uint4 uh; uh.x = hp[0]; uh.y = hp[1]; uh.z = hp[2]; uh.w = hp[3];
    uint4 ul; ul.x = lp[0]; ul.y = lp[1]; ul.z = lp[2]; ul.w = lp[3];
    *reinterpret_cast<uint4*>(&s_xh[rowl][col0]) = uh;
    *reinterpret_cast<uint4*>(&s_xl[rowl][col0]) = ul;
  }
  __syncthreads();

  short8 xh[4], xl[4];
  #pragma unroll
  for (int ks = 0; ks < 4; ++ks){
    xh[ks] = ld8(&s_xh[c][ks * 32 + g * 8]);
    xl[ks] = ld8(&s_xl[c][ks * 32 + g * 8]);
  }

  // ---- gate (compensated) ----
  float gwv[4];
  {
    f32x4 ga = z4;
    #pragma unroll
    for (int ks = 0; ks < 4; ++ks){
      int off = GATE_O + (c & 3) * 128 + ks * 32 + g * 8;
      short8 wh = ld8(whi + off), wl = ld8(wlo + off);
      ga = MFMA(xh[ks], wh, ga);
      ga = MFMA(xl[ks], wh, ga);
      ga = MFMA(xh[ks], wl, ga);
    }
    float gb = gate_b[c & 3];
    #pragma unroll
    for (int r = 0; r < 4; ++r){
      float le = ga[r] + gb;
      float mx = fmaxf(le, __shfl_xor(le, 1, 64));
      mx = fmaxf(mx, __shfl_xor(mx, 2, 64));
      float ev = __expf(le - mx);
      float sm = ev + __shfl_xor(ev, 1, 64);
      sm += __shfl_xor(sm, 2, 64);
      gwv[r] = ev / sm;
    }
  }

  // ---- MoE (compensated) ----
  f32x4 mrr = z4, mri = z4;
  #pragma unroll
  for (int e = 0; e < 4; ++e){
    float gwr[4];
    #pragma unroll
    for (int r = 0; r < 4; ++r) gwr[r] = __shfl(gwv[r], g * 16 + e, 64);
    f32x4 er = z4, ei = z4;
    #pragma unroll
    for (int ks = 0; ks < 2; ++ks){
      int boff = e * 4096 + col * 64 + ks * 32 + g * 8;
      short8 wrh = ld8(whi + EWR_O + boff);
      short8 wrl = ld8(wlo + EWR_O + boff);
      short8 wih = ld8(whi + EWI_O + boff);
      short8 wil = ld8(wlo + EWI_O + boff);
      short8 wihn = neg8(wih), wiln = neg8(wil);
      er = MFMA(xh[ks],   wrh, er);   ei = MFMA(xh[ks+2], wrh, ei);
      er = MFMA(xl[ks],   wrh, er);   ei = MFMA(xl[ks+2], wrh, ei);
      er = MFMA(xh[ks],   wrl, er);   ei = MFMA(xh[ks+2], wrl, ei);
      er = MFMA(xh[ks+2], wihn, er);  ei = MFMA(xh[ks],   wih, ei);
      er = MFMA(xl[ks+2], wihn, er);  ei = MFMA(xl[ks],   wih, ei);
      er = MFMA(xh[ks+2], wiln, er);  ei = MFMA(xh[ks],   wil, ei);
    }
    #pragma unroll
    for (int r = 0; r < 4; ++r){
      mrr[r] = fmaf(gwr[r], er[r], mrr[r]);
      mri[r] = fmaf(gwr[r], ei[r], mri[r]);
    }
  }

  // ---- ComplexLayerNorm (ddof=1) + ModReLU ----
  {
    float hh[4], mg[4];
    #pragma unroll
    for (int r = 0; r < 4; ++r){
      hh[r] = sqrtf(mrr[r] * mrr[r] + mri[r] * mri[r]);
      mg[r] = hh[r] + EPS_F;
    }
    #pragma unroll
    for (int r = 0; r < 4; ++r){
      float sx  = qsum16(mg[r]);
      float sxx = qsum16(mg[r] * mg[r]);
      if (c == 0){ s_red[w][g * 4 + r][0] = sx; s_red[w][g * 4 + r][1] = sxx; }
    }
    __syncthreads();
    float lsc = ln_scale[col], lsh = ln_shift[col], mb = mod_bias[col];
    #pragma unroll
    for (int r = 0; r < 4; ++r){
      int rr = g * 4 + r;
      float SX  = s_red[0][rr][0] + s_red[1][rr][0] + s_red[2][rr][0] + s_red[3][rr][0];
      float SXX = s_red[0][rr][1] + s_red[1][rr][1] + s_red[2][rr][1] + s_red[3][rr][1];
      float mean = SX * (1.0f / 64.0f);
      float var  = (SXX - SX * mean) * (1.0f / 63.0f);
      float istd = rsqrtf(var + EPS_F);
      float nm = (mg[r] - mean) * istd * lsc + lsh;
      float lr, li;
      if (hh[r] > 0.f){ float ih = 1.0f / hh[r]; lr = nm * mrr[r] * ih; li = nm * mri[r] * ih; }
      else            { lr = nm; li = 0.f; }
      float nrm = sqrtf(lr * lr + li * li) + EPS_F;
      float sf  = fmaxf(nrm + mb, 0.f) / nrm;
      s_a[rr][col]      = f2bf(lr * sf);
      s_a[rr][64 + col] = f2bf(li * sf);
    }
  }
  __syncthreads();

  // ---- ctx gate ----
  f32x4 cwa[2];
  #pragma unroll
  for (int ii = 0; ii < 2; ++ii){
    int ct8 = w + ii * 4;
    f32x4 a = z4;
    #pragma unroll
    for (int ks = 0; ks < 4; ++ks)
      a = MFMA(xh[ks], ld8(whi + CTX_O + (ct8 * 16 + c) * 128 + ks * 32 + g * 8), a);
    float cb = ctx_b[ct8 * 16 + c];
    #pragma unroll
    for (int r = 0; r < 4; ++r) cwa[ii][r] = 1.0f / (1.0f + __expf(-(a[r] + cb)));
  }

  // ---- residual ----
  #pragma unroll
  for (int ii = 0; ii < 2; ++ii){
    int ct8 = w + ii * 4;
    f32x4 a = z4;
    #pragma unroll
    for (int ks = 0; ks < 4; ++ks)
      a = MFMA(xh[ks], ld8(whi + RES_O + (ct8 * 16 + c) * 128 + ks * 32 + g * 8), a);
    float rb = res_b[ct8 * 16 + c];
    #pragma unroll
    for (int r = 0; r < 4; ++r)
      resb[(size_t)(row0 + 4 * g + r) * 128 + ct8 * 16 + c] = 0.1f * (a[r] + rb);
  }

  // ---- QKV ----
  short8 ar_[2], ai_[2], ain_[2];
  #pragma unroll
  for (int ks = 0; ks < 2; ++ks){
    ar_[ks]  = ld8(&s_a[c][ks * 32 + g * 8]);
    ai_[ks]  = ld8(&s_a[c][64 + ks * 32 + g * 8]);
    ain_[ks] = neg8(ai_[ks]);
  }

  #pragma unroll
  for (int mat = 0; mat < 3; ++mat){
    int roff = (mat == 0) ? QWR_O : (mat == 1) ? KWR_O : VWR_O;
    int ioff = (mat == 0) ? QWI_O : (mat == 1) ? KWI_O : VWI_O;
    f32x4 orr = z4, oii = z4;
    #pragma unroll
    for (int ks = 0; ks < 2; ++ks){
      int boff = col * 64 + ks * 32 + g * 8;
      short8 wrh = ld8(whi + roff + boff);
      short8 wrl = ld8(wlo + roff + boff);
      short8 wih = ld8(whi + ioff + boff);
      short8 wil = ld8(wlo + ioff + boff);
      orr = MFMA(ar_[ks],  wrh, orr);  oii = MFMA(ai_[ks], wrh, oii);
      orr = MFMA(ar_[ks],  wrl, orr);  oii = MFMA(ai_[ks], wrl, oii);
      orr = MFMA(ain_[ks], wih, orr);  oii = MFMA(ar_[ks], wih, oii);
      orr = MFMA(ain_[ks], wil, orr);  oii = MFMA(ar_[ks], wil, oii);
    }
    if (mat == 0){
      #pragma unroll
      for (int r = 0; r < 4; ++r){
        size_t row = row0 + 4 * g + r;
        qf[row * 128 + col]      = f2bf(orr[r] * cwa[0][r] * QSC);
        qf[row * 128 + 64 + col] = f2bf(oii[r] * cwa[1][r] * QSC);
      }
    } else if (mat == 1){
      #pragma unroll
      for (int r = 0; r < 4; ++r){
        size_t row = row0 + 4 * g + r;
        kf[row * 128 + col]      = f2bf(orr[r]);
        kf[row * 128 + 64 + col] = f2bf(oii[r]);
      }
    } else {
      #pragma unroll
      for (int r = 0; r < 4; ++r){
        s_tv[col][4 * g + r]      = f2bf(orr[r]);
        s_tv[64 + col][4 * g + r] = f2bf(oii[r]);
      }
    }
  }
  __syncthreads();

  {
    int d = tid >> 1, half = tid & 1;
    uint2 t0 = *reinterpret_cast<const uint2*>(&s_tv[d][half * 8]);
    uint2 t1 = *reinterpret_cast<const uint2*>(&s_tv[d][half * 8 + 4]);
    uint4 o; o.x = t0.x; o.y = t0.y; o.z = t1.x; o.w = t1.y;
    *reinterpret_cast<uint4*>(vt + (size_t)d * 8192 + row0 + half * 8) = o;
  }
}

// ---- online softmax for one 16-q half; THR=8 defer-max (exact bookkeeping) ----
__device__ __forceinline__ short8 sm_half(
    const f32x4& s0, const f32x4& s1, float& mrun, float& lrun,
    f32x4* __restrict__ oacc, uint_t* __restrict__ prow, int g)
{
  float t0 = fmaxf(fmaxf(fmaxf(s0[0], s0[1]), fmaxf(s0[2], s0[3])),
                   fmaxf(fmaxf(s1[0], s1[1]), fmaxf(s1[2], s1[3])));
  t0 = fmaxf(t0, __shfl_xor(t0, 16, 64));
  t0 = fmaxf(t0, __shfl_xor(t0, 32, 64));
  if (__any(t0 > mrun + 8.0f)){
    float mnew = fmaxf(mrun, t0);
    float fac  = exp2f(mrun - mnew);
    lrun *= fac;
    #pragma unroll
    for (int dt = 0; dt < 8; ++dt){
      oacc[dt][0] *= fac; oacc[dt][1] *= fac; oacc[dt][2] *= fac; oacc[dt][3] *= fac;
    }
    mrun = mnew;
  }
  float p00 = exp2f(s0[0] - mrun), p01 = exp2f(s0[1] - mrun);
  float p02 = exp2f(s0[2] - mrun), p03 = exp2f(s0[3] - mrun);
  float p10 = exp2f(s1[0] - mrun), p11 = exp2f(s1[1] - mrun);
  float p12 = exp2f(s1[2] - mrun), p13 = exp2f(s1[3] - mrun);
  float ps = ((p00 + p01) + (p02 + p03)) + ((p10 + p11) + (p12 + p13));
  ps += __shfl_xor(ps, 16, 64);
  ps += __shfl_xor(ps, 32, 64);
  lrun += ps;
  uint2 w0; w0.x = cvtpk(p00, p01); w0.y = cvtpk(p02, p03);
  uint2 w1; w1.x = cvtpk(p10, p11); w1.y = cvtpk(p12, p13);
  *reinterpret_cast<uint2*>(prow + 2 * g)     = w0;
  *reinterpret_cast<uint2*>(prow + 8 + 2 * g) = w1;
  return *reinterpret_cast<const short8*>(prow + 4 * g);
}

// ---- MFMA flash attention: 32 q/wave, KVBLK=64 staged per barrier pair ----
// Same verified 2-barrier structure (stage between barriers, then compute),
// amortized over 64 KV rows: half the barrier/drain count, 2x staging MLP.
// BANNED (NaN): reg-prefetch (r11/r12), LDS double-buffer (r16).
// BANNED (spill): launch_bounds waves/EU 4/6 (r14/r15); (256,3) is stable.
template<int NCH_T>
__global__ __launch_bounds__(256, 3) void attn_mfma(
    const ushort_t* __restrict__ qf, const ushort_t* __restrict__ kf, const ushort_t* __restrict__ vt,
    ushort_t* __restrict__ pacc, float* __restrict__ pm, float* __restrict__ pl)
{
  constexpr int CHUNK_T = 8192 / NCH_T;
  constexpr int TILES_T = CHUNK_T / 64;

  const int tid  = threadIdx.x;
  const int lane = tid & 63;
  const int w    = tid >> 6;
  const int g    = lane >> 4;
  const int hl   = lane & 15;
  const int qb   = blockIdx.x & 63;
  const int jc   = blockIdx.x >> 6;
  const int qw   = qb * 128 + w * 32;
  const int qrA  = qw + hl;
  const int qrB  = qw + 16 + hl;

  __shared__ ushort_t s_k[64][128];    // XOR-swizzled: col ^= (row&7)*8
  __shared__ ushort_t s_vt[128][64];   // XOR-swizzled: col ^= (row&7)*8
  __shared__ uint_t   s_p32[4][2][16][20];

  const int kjj0 = tid >> 4;            // 0..15, rows +i*16
  const int kkk  = (tid & 15) * 8;
  const int vd0  = tid >> 3;            // 0..31, rows +i*32
  const int vjo  = (tid & 7) * 8;
  const int jstart = jc * CHUNK_T;

  short8 qfA[4], qfB[4];
  #pragma unroll
  for (int kt = 0; kt < 4; ++kt){
    qfA[kt] = ld8(qf + (size_t)qrA * 128 + kt * 32 + g * 8);
    qfB[kt] = ld8(qf + (size_t)qrB * 128 + kt * 32 + g * 8);
  }

  f32x4 oA[8], oB[8];
  #pragma unroll
  for (int dt = 0; dt < 8; ++dt){
    oA[dt] = (f32x4){0.f, 0.f, 0.f, 0.f};
    oB[dt] = (f32x4){0.f, 0.f, 0.f, 0.f};
  }
  float mA = -3.0e38f, lA = 0.f, mB = -3.0e38f, lB = 0.f;

  for (int t = 0; t < TILES_T; ++t){
    const int jb = jstart + t * 64;
    __syncthreads();
    #pragma unroll
    for (int i = 0; i < 4; ++i){
      int kr = kjj0 + i * 16;
      *reinterpret_cast<uint4*>(&s_k[kr][kkk ^ ((kr & 7) * 8)]) =
          *reinterpret_cast<const uint4*>(kf + (size_t)(jb + kr) * 128 + kkk);
      int vr = vd0 + i * 32;
      *reinterpret_cast<uint4*>(&s_vt[vr][vjo ^ ((vr & 7) * 8)]) =
          *reinterpret_cast<const uint4*>(vt + (size_t)vr * 8192 + jb + vjo);
    }
    __syncthreads();

    #pragma unroll
    for (int sub = 0; sub < 2; ++sub){
      // ---- QK^T for both q-halves over 32-row subtile ----
      f32x4 sA[2], sB[2];
      #pragma unroll
      for (int jt = 0; jt < 2; ++jt){
        sA[jt] = (f32x4){0.f, 0.f, 0.f, 0.f};
        sB[jt] = (f32x4){0.f, 0.f, 0.f, 0.f};
        #pragma unroll
        for (int kt = 0; kt < 4; ++kt){
          short8 kfr = ld8(&s_k[sub * 32 + jt * 16 + hl][(kt * 32 + g * 8) ^ ((hl & 7) * 8)]);
          sA[jt] = __builtin_amdgcn_mfma_f32_16x16x32_bf16(kfr, qfA[kt], sA[jt], 0, 0, 0);
          sB[jt] = __builtin_amdgcn_mfma_f32_16x16x32_bf16(kfr, qfB[kt], sB[jt], 0, 0, 0);
        }
      }

      short8 pfA = sm_half(sA[0], sA[1], mA, lA, oA, &s_p32[w][0][hl][0], g);
      short8 pfB = sm_half(sB[0], sB[1], mB, lB, oB, &s_p32[w][1][hl][0], g);

      // ---- PV for both halves ----
      #pragma unroll
      for (int dt = 0; dt < 8; ++dt){
        short8 vfr = ld8(&s_vt[dt * 16 + hl][(sub * 32 + g * 8) ^ ((hl & 7) * 8)]);
        oA[dt] = __builtin_amdgcn_mfma_f32_16x16x32_bf16(vfr, pfA, oA[dt], 0, 0, 0);
        oB[dt] = __builtin_amdgcn_mfma_f32_16x16x32_bf16(vfr, pfB, oB[dt], 0, 0, 0);
      }
    }
  }

  // ---- write partials (bf16, pair-packed 8B stores) ----
  #pragma unroll
  for (int dt = 0; dt < 8; ++dt){
    uint2 a;
    a.x = cvtpk(oA[dt][0], oA[dt][1]);
    a.y = cvtpk(oA[dt][2], oA[dt][3]);
    *reinterpret_cast<uint2*>(pacc + ((size_t)jc * 8192 + qrA) * 128 + dt * 16 + 4 * g) = a;
    uint2 b;
    b.x = cvtpk(oB[dt][0], oB[dt][1]);
    b.y = cvtpk(oB[dt][2], oB[dt][3]);
    *reinterpret_cast<uint2*>(pacc + ((size_t)jc * 8192 + qrB) * 128 + dt * 16 + 4 * g) = b;
  }
  if (g == 0){
    pm[jc * 8192 + qrA] = mA;  pl[jc * 8192 + qrA] = lA;
    pm[jc * 8192 + qrB] = mB;  pl[jc * 8192 + qrB] = lB;
  }
}

// ---- combine chunk partials + residual + halt/stack heads ----
template<int NCH_T>
__global__ __launch_bounds__(256, 1) void combine_kernel(
    const ushort_t* __restrict__ pacc, const float* __restrict__ pm, const float* __restrict__ pl,
    const float* __restrict__ resb,
    const float* __restrict__ halt_W, const float* __restrict__ halt_b,
    const float* __restrict__ stack_W, const float* __restrict__ stack_b,
    float* __restrict__ out)
{
  const int tid  = threadIdx.x;
  const int lane = tid & 63;
  const int w    = tid >> 6;
  const int q    = blockIdx.x * 4 + w;

  float mv[NCH_T], M = -3.0e38f;
  #pragma unroll
  for (int c = 0; c < NCH_T; ++c){ mv[c] = pm[c * 8192 + q]; M = fmaxf(M, mv[c]); }
  float f[NCH_T]; float L = 0.f;
  #pragma unroll
  for (int c = 0; c < NCH_T; ++c){ f[c] = exp2f(mv[c] - M); L += pl[c * 8192 + q] * f[c]; }
  float invL = 1.0f / L;

  float o0 = 0.f, o1 = 0.f;
  #pragma unroll
  for (int c = 0; c < NCH_T; ++c){
    const ushort_t* pa = pacc + ((size_t)c * 8192 + q) * 128;
    o0 += bf2f(pa[lane])      * f[c];
    o1 += bf2f(pa[64 + lane]) * f[c];
  }
  o0 = o0 * invL + resb[(size_t)q * 128 + lane];
  o1 = o1 * invL + resb[(size_t)q * 128 + 64 + lane];
  out[(size_t)q * 64 + lane] = o0;
  out[(size_t)8192 * 64 + (size_t)q * 64 + lane] = o1;

  float ssq  = wave_sum64(o0 * o0 + o1 * o1);
  float invn = 1.0f / (sqrtf(ssq) + 1e-6f);
  float zn0 = o0 * invn, zn1 = o1 * invn;
  float hp = wave_sum64(zn0 * halt_W[lane]        + zn1 * halt_W[64 + lane]);
  float s0 = wave_sum64(zn0 * stack_W[lane]       + zn1 * stack_W[64 + lane]);
  float s1 = wave_sum64(zn0 * stack_W[128 + lane] + zn1 * stack_W[192 + lane]);
  float s2 = wave_sum64(zn0 * stack_W[256 + lane] + zn1 * stack_W[320 + lane]);
  if (lane == 0){
    out[1048576 + q] = hp + halt_b[0];
    out[1056768 + (size_t)q * 3 + 0] = s0 + stack_b[0];
    out[1056768 + (size_t)q * 3 + 1] = s1 + stack_b[1];
    out[1056768 + (size_t)q * 3 + 2] = s2 + stack_b[2];
  }
}

extern "C" void kernel_launch(void* const* d_in, const int* in_sizes, int n_in,
                              void* d_out, int out_size, void* d_ws, size_t ws_size,
                              hipStream_t stream){
  const float* z_real  = (const float*)d_in[0];
  const float* z_imag  = (const float*)d_in[1];
  const float* gate_W  = (const float*)d_in[2];
  const float* gate_b  = (const float*)d_in[3];
  const float* exp_Wr  = (const float*)d_in[4];
  const float* exp_Wi  = (const float*)d_in[5];
  const float* ln_scale= (const float*)d_in[6];
  const float* ln_shift= (const float*)d_in[7];
  const float* mod_bias= (const float*)d_in[8];
  const float* q_Wr    = (const float*)d_in[9];
  const float* q_Wi    = (const float*)d_in[10];
  const float* k_Wr    = (const float*)d_in[11];
  const float* k_Wi    = (const float*)d_in[12];
  const float* v_Wr    = (const float*)d_in[13];
  const float* v_Wi    = (const float*)d_in[14];
  const float* ctx_W   = (const float*)d_in[15];
  const float* ctx_b   = (const float*)d_in[16];
  const float* res_W   = (const float*)d_in[17];
  const float* res_b   = (const float*)d_in[18];
  const float* halt_W  = (const float*)d_in[19];
  const float* halt_b  = (const float*)d_in[20];
  const float* stack_W = (const float*)d_in[21];
  const float* stack_b = (const float*)d_in[22];

  auto need = [&](int nch)->size_t{
    size_t b = (size_t)3 * 8192 * 128 * 2;                       // qbf,kbf,vtb bf16
    b += (size_t)8192 * 128 * 4;                                 // resb fp32
    b += (size_t)nch * 8192 * 128 * 2;                           // pacc bf16
    b += (size_t)2 * nch * 8192 * 4;                             // pm, pl
    b += (size_t)2 * WTOT * 2;                                   // whi, wlo
    return b;
  };
  const int nch = (ws_size >= need(16)) ? 16 : 8;

  ushort_t* qbf = (ushort_t*)d_ws;
  ushort_t* kbf = qbf + (size_t)8192*128;
  ushort_t* vtb = kbf + (size_t)8192*128;
  float* resb = (float*)(vtb + (size_t)8192*128);
  ushort_t* pacc = (ushort_t*)(resb + (size_t)8192*128);
  float* pm   = (float*)(pacc + (size_t)nch*8192*128);
  float* pl   = pm   + (size_t)nch*8192;
  ushort_t* whi = (ushort_t*)(pl + (size_t)nch*8192);
  ushort_t* wlo = whi + WTOT;

  wconv_kernel<<<(WTOT + 255) / 256, 256, 0, stream>>>(gate_W, exp_Wr, exp_Wi,
      q_Wr, q_Wi, k_Wr, k_Wi, v_Wr, v_Wi, ctx_W, res_W, whi, wlo);
  prep_kernel<<<512, 256, 0, stream>>>(z_real, z_imag, whi, wlo, gate_b,
      ln_scale, ln_shift, mod_bias, ctx_b, res_b, qbf, kbf, vtb, resb);
  if (nch == 16){
    attn_mfma<16><<<64*16, 256, 0, stream>>>(qbf, kbf, vtb, pacc, pm, pl);
    combine_kernel<16><<<2048, 256, 0, stream>>>(pacc, pm, pl, resb,
        halt_W, halt_b, stack_W, stack_b, (float*)d_out);
  } else {
    attn_mfma<8><<<64*8, 256, 0, stream>>>(qbf, kbf, vtb, pacc, pm, pl);
    combine_kernel<8><<<2048, 256, 0, stream>>>(pacc, pm, pl, resb,
        halt_W, halt_b, stack_W, stack_b, (float*)d_out);
  }
}

// Round 19
// 103.676 us; speedup vs baseline: 4.4173x; 1.0101x over previous
//
#include <hip/hip_runtime.h>
#include <math.h>

#define EPS_F 1e-6f
#define QSC   (0.125f * 1.44269504088896340736f)   // ATTN_SCALE * log2(e)

// weight-buffer offsets (elements) in whi/wlo
#define GATE_O 0
#define EWR_O  512
#define EWI_O  16896
#define QWR_O  33280
#define QWI_O  37376
#define KWR_O  41472
#define KWI_O  45568
#define VWR_O  49664
#define VWI_O  53760
#define CTX_O  57856
#define RES_O  74240
#define WTOT   90624

typedef __attribute__((ext_vector_type(8))) short short8;
typedef __attribute__((ext_vector_type(4))) float f32x4;
typedef unsigned short ushort_t;
typedef unsigned int uint_t;

__device__ __forceinline__ ushort_t f2bf(float x){
  uint_t u = __float_as_uint(x);
  u += 0x7fffu + ((u >> 16) & 1u);
  return (ushort_t)(u >> 16);
}
__device__ __forceinline__ float bf2f(ushort_t u){
  return __uint_as_float(((uint_t)u) << 16);
}
// hardware packed f32->bf16 (RNE), 1 inst for 2 values
__device__ __forceinline__ uint_t cvtpk(float lo, float hi){
  uint_t r;
  asm("v_cvt_pk_bf16_f32 %0, %1, %2" : "=v"(r) : "v"(lo), "v"(hi));
  return r;
}

__device__ __forceinline__ float wave_sum64(float v){
  #pragma unroll
  for (int m = 32; m > 0; m >>= 1) v += __shfl_xor(v, m, 64);
  return v;
}
__device__ __forceinline__ float qsum16(float v){
  #pragma unroll
  for (int m = 1; m < 16; m <<= 1) v += __shfl_xor(v, m, 64);
  return v;
}

__device__ __forceinline__ short8 neg8(short8 v){
  uint4 u = *reinterpret_cast<uint4*>(&v);
  u.x ^= 0x80008000u; u.y ^= 0x80008000u; u.z ^= 0x80008000u; u.w ^= 0x80008000u;
  return *reinterpret_cast<short8*>(&u);
}
__device__ __forceinline__ short8 ld8(const ushort_t* __restrict__ p){
  return *reinterpret_cast<const short8*>(p);
}

#define MFMA(a,b,c) __builtin_amdgcn_mfma_f32_16x16x32_bf16((a),(b),(c),0,0,0)

// ============ weight conversion: fp32 -> bf16 hi/lo, fragment-ready ============
__global__ __launch_bounds__(256) void wconv_kernel(
    const float* __restrict__ gate_W, const float* __restrict__ exp_Wr,
    const float* __restrict__ exp_Wi,
    const float* __restrict__ q_Wr, const float* __restrict__ q_Wi,
    const float* __restrict__ k_Wr, const float* __restrict__ k_Wi,
    const float* __restrict__ v_Wr, const float* __restrict__ v_Wi,
    const float* __restrict__ ctx_W, const float* __restrict__ res_W,
    ushort_t* __restrict__ whi, ushort_t* __restrict__ wlo)
{
  int i = blockIdx.x * 256 + threadIdx.x;
  if (i >= WTOT) return;
  float v;
  if      (i < EWR_O) v = gate_W[i - GATE_O];
  else if (i < EWI_O) v = exp_Wr[i - EWR_O];
  else if (i < QWR_O) v = exp_Wi[i - EWI_O];
  else if (i < QWI_O) v = q_Wr[i - QWR_O];
  else if (i < KWR_O) v = q_Wi[i - QWI_O];
  else if (i < KWI_O) v = k_Wr[i - KWR_O];
  else if (i < VWR_O) v = k_Wi[i - KWI_O];
  else if (i < VWI_O) v = v_Wr[i - VWR_O];
  else if (i < CTX_O) v = v_Wi[i - VWI_O];
  else if (i < RES_O) v = ctx_W[i - CTX_O];
  else                v = res_W[i - RES_O];
  ushort_t h = f2bf(v);
  whi[i] = h;
  wlo[i] = f2bf(v - bf2f(h));
}

// ============ prep v3: MFMA everywhere, 4 waves/block, wave = col-tile ============
__global__ __launch_bounds__(256, 4) void prep_kernel(
    const float* __restrict__ z_real, const float* __restrict__ z_imag,
    const ushort_t* __restrict__ whi, const ushort_t* __restrict__ wlo,
    const float* __restrict__ gate_b,
    const float* __restrict__ ln_scale, const float* __restrict__ ln_shift,
    const float* __restrict__ mod_bias,
    const float* __restrict__ ctx_b, const float* __restrict__ res_b,
    ushort_t* __restrict__ qf, ushort_t* __restrict__ kf, ushort_t* __restrict__ vt,
    float* __restrict__ resb)
{
  const int tid  = threadIdx.x;
  const int lane = tid & 63;
  const int w    = tid >> 6;
  const int g    = lane >> 4;
  const int c    = lane & 15;
  const int row0 = blockIdx.x * 16;
  const int col  = w * 16 + c;
  const f32x4 z4 = {0.f, 0.f, 0.f, 0.f};

  __shared__ ushort_t s_xh[16][136];
  __shared__ ushort_t s_xl[16][136];
  __shared__ ushort_t s_a [16][136];
  __shared__ ushort_t s_tv[128][20];
  __shared__ float    s_red[4][16][2];

  {
    int rowl = tid >> 4;
    int col0 = (tid & 15) * 8;
    const float* src = (col0 < 64) ? (z_real + (size_t)(row0 + rowl) * 64 + col0)
                                   : (z_imag + (size_t)(row0 + rowl) * 64 + (col0 - 64));
    float4 a = *reinterpret_cast<const float4*>(src);
    float4 b = *reinterpret_cast<const float4*>(src + 4);
    float f[8] = {a.x, a.y, a.z, a.w, b.x, b.y, b.z, b.w};
    uint_t hp[4], lp[4];
    #pragma unroll
    for (int e = 0; e < 4; ++e){
      ushort_t h0 = f2bf(f[2*e]), h1 = f2bf(f[2*e+1]);
      hp[e] = (uint_t)h0 | ((uint_t)h1 << 16);
      lp[e] = (uint_t)f2bf(f[2*e]   - bf2f(h0)) |
              ((uint_t)f2bf(f[2*e+1] - bf2f(h1)) << 16);
    }
    uint4 uh; uh.x = hp[0]; uh.y = hp[1]; uh.z = hp[2]; uh.w = hp[3];
    uint4 ul; ul.x = lp[0]; ul.y = lp[1]; ul.z = lp[2]; ul.w = lp[3];
    *reinterpret_cast<uint4*>(&s_xh[rowl][col0]) = uh;
    *reinterpret_cast<uint4*>(&s_xl[rowl][col0]) = ul;
  }
  __syncthreads();

  short8 xh[4], xl[4];
  #pragma unroll
  for (int ks = 0; ks < 4; ++ks){
    xh[ks] = ld8(&s_xh[c][ks * 32 + g * 8]);
    xl[ks] = ld8(&s_xl[c][ks * 32 + g * 8]);
  }

  // ---- gate (compensated) ----
  float gwv[4];
  {
    f32x4 ga = z4;
    #pragma unroll
    for (int ks = 0; ks < 4; ++ks){
      int off = GATE_O + (c & 3) * 128 + ks * 32 + g * 8;
      short8 wh = ld8(whi + off), wl = ld8(wlo + off);
      ga = MFMA(xh[ks], wh, ga);
      ga = MFMA(xl[ks], wh, ga);
      ga = MFMA(xh[ks], wl, ga);
    }
    float gb = gate_b[c & 3];
    #pragma unroll
    for (int r = 0; r < 4; ++r){
      float le = ga[r] + gb;
      float mx = fmaxf(le, __shfl_xor(le, 1, 64));
      mx = fmaxf(mx, __shfl_xor(mx, 2, 64));
      float ev = __expf(le - mx);
      float sm = ev + __shfl_xor(ev, 1, 64);
      sm += __shfl_xor(sm, 2, 64);
      gwv[r] = ev / sm;
    }
  }

  // ---- MoE (compensated) ----
  f32x4 mrr = z4, mri = z4;
  #pragma unroll
  for (int e = 0; e < 4; ++e){
    float gwr[4];
    #pragma unroll
    for (int r = 0; r < 4; ++r) gwr[r] = __shfl(gwv[r], g * 16 + e, 64);
    f32x4 er = z4, ei = z4;
    #pragma unroll
    for (int ks = 0; ks < 2; ++ks){
      int boff = e * 4096 + col * 64 + ks * 32 + g * 8;
      short8 wrh = ld8(whi + EWR_O + boff);
      short8 wrl = ld8(wlo + EWR_O + boff);
      short8 wih = ld8(whi + EWI_O + boff);
      short8 wil = ld8(wlo + EWI_O + boff);
      short8 wihn = neg8(wih), wiln = neg8(wil);
      er = MFMA(xh[ks],   wrh, er);   ei = MFMA(xh[ks+2], wrh, ei);
      er = MFMA(xl[ks],   wrh, er);   ei = MFMA(xl[ks+2], wrh, ei);
      er = MFMA(xh[ks],   wrl, er);   ei = MFMA(xh[ks+2], wrl, ei);
      er = MFMA(xh[ks+2], wihn, er);  ei = MFMA(xh[ks],   wih, ei);
      er = MFMA(xl[ks+2], wihn, er);  ei = MFMA(xl[ks],   wih, ei);
      er = MFMA(xh[ks+2], wiln, er);  ei = MFMA(xh[ks],   wil, ei);
    }
    #pragma unroll
    for (int r = 0; r < 4; ++r){
      mrr[r] = fmaf(gwr[r], er[r], mrr[r]);
      mri[r] = fmaf(gwr[r], ei[r], mri[r]);
    }
  }

  // ---- ComplexLayerNorm (ddof=1) + ModReLU ----
  {
    float hh[4], mg[4];
    #pragma unroll
    for (int r = 0; r < 4; ++r){
      hh[r] = sqrtf(mrr[r] * mrr[r] + mri[r] * mri[r]);
      mg[r] = hh[r] + EPS_F;
    }
    #pragma unroll
    for (int r = 0; r < 4; ++r){
      float sx  = qsum16(mg[r]);
      float sxx = qsum16(mg[r] * mg[r]);
      if (c == 0){ s_red[w][g * 4 + r][0] = sx; s_red[w][g * 4 + r][1] = sxx; }
    }
    __syncthreads();
    float lsc = ln_scale[col], lsh = ln_shift[col], mb = mod_bias[col];
    #pragma unroll
    for (int r = 0; r < 4; ++r){
      int rr = g * 4 + r;
      float SX  = s_red[0][rr][0] + s_red[1][rr][0] + s_red[2][rr][0] + s_red[3][rr][0];
      float SXX = s_red[0][rr][1] + s_red[1][rr][1] + s_red[2][rr][1] + s_red[3][rr][1];
      float mean = SX * (1.0f / 64.0f);
      float var  = (SXX - SX * mean) * (1.0f / 63.0f);
      float istd = rsqrtf(var + EPS_F);
      float nm = (mg[r] - mean) * istd * lsc + lsh;
      float lr, li;
      if (hh[r] > 0.f){ float ih = 1.0f / hh[r]; lr = nm * mrr[r] * ih; li = nm * mri[r] * ih; }
      else            { lr = nm; li = 0.f; }
      float nrm = sqrtf(lr * lr + li * li) + EPS_F;
      float sf  = fmaxf(nrm + mb, 0.f) / nrm;
      s_a[rr][col]      = f2bf(lr * sf);
      s_a[rr][64 + col] = f2bf(li * sf);
    }
  }
  __syncthreads();

  // ---- ctx gate ----
  f32x4 cwa[2];
  #pragma unroll
  for (int ii = 0; ii < 2; ++ii){
    int ct8 = w + ii * 4;
    f32x4 a = z4;
    #pragma unroll
    for (int ks = 0; ks < 4; ++ks)
      a = MFMA(xh[ks], ld8(whi + CTX_O + (ct8 * 16 + c) * 128 + ks * 32 + g * 8), a);
    float cb = ctx_b[ct8 * 16 + c];
    #pragma unroll
    for (int r = 0; r < 4; ++r) cwa[ii][r] = 1.0f / (1.0f + __expf(-(a[r] + cb)));
  }

  // ---- residual ----
  #pragma unroll
  for (int ii = 0; ii < 2; ++ii){
    int ct8 = w + ii * 4;
    f32x4 a = z4;
    #pragma unroll
    for (int ks = 0; ks < 4; ++ks)
      a = MFMA(xh[ks], ld8(whi + RES_O + (ct8 * 16 + c) * 128 + ks * 32 + g * 8), a);
    float rb = res_b[ct8 * 16 + c];
    #pragma unroll
    for (int r = 0; r < 4; ++r)
      resb[(size_t)(row0 + 4 * g + r) * 128 + ct8 * 16 + c] = 0.1f * (a[r] + rb);
  }

  // ---- QKV ----
  short8 ar_[2], ai_[2], ain_[2];
  #pragma unroll
  for (int ks = 0; ks < 2; ++ks){
    ar_[ks]  = ld8(&s_a[c][ks * 32 + g * 8]);
    ai_[ks]  = ld8(&s_a[c][64 + ks * 32 + g * 8]);
    ain_[ks] = neg8(ai_[ks]);
  }

  #pragma unroll
  for (int mat = 0; mat < 3; ++mat){
    int roff = (mat == 0) ? QWR_O : (mat == 1) ? KWR_O : VWR_O;
    int ioff = (mat == 0) ? QWI_O : (mat == 1) ? KWI_O : VWI_O;
    f32x4 orr = z4, oii = z4;
    #pragma unroll
    for (int ks = 0; ks < 2; ++ks){
      int boff = col * 64 + ks * 32 + g * 8;
      short8 wrh = ld8(whi + roff + boff);
      short8 wrl = ld8(wlo + roff + boff);
      short8 wih = ld8(whi + ioff + boff);
      short8 wil = ld8(wlo + ioff + boff);
      orr = MFMA(ar_[ks],  wrh, orr);  oii = MFMA(ai_[ks], wrh, oii);
      orr = MFMA(ar_[ks],  wrl, orr);  oii = MFMA(ai_[ks], wrl, oii);
      orr = MFMA(ain_[ks], wih, orr);  oii = MFMA(ar_[ks], wih, oii);
      orr = MFMA(ain_[ks], wil, orr);  oii = MFMA(ar_[ks], wil, oii);
    }
    if (mat == 0){
      #pragma unroll
      for (int r = 0; r < 4; ++r){
        size_t row = row0 + 4 * g + r;
        qf[row * 128 + col]      = f2bf(orr[r] * cwa[0][r] * QSC);
        qf[row * 128 + 64 + col] = f2bf(oii[r] * cwa[1][r] * QSC);
      }
    } else if (mat == 1){
      #pragma unroll
      for (int r = 0; r < 4; ++r){
        size_t row = row0 + 4 * g + r;
        kf[row * 128 + col]      = f2bf(orr[r]);
        kf[row * 128 + 64 + col] = f2bf(oii[r]);
      }
    } else {
      #pragma unroll
      for (int r = 0; r < 4; ++r){
        s_tv[col][4 * g + r]      = f2bf(orr[r]);
        s_tv[64 + col][4 * g + r] = f2bf(oii[r]);
      }
    }
  }
  __syncthreads();

  {
    int d = tid >> 1, half = tid & 1;
    uint2 t0 = *reinterpret_cast<const uint2*>(&s_tv[d][half * 8]);
    uint2 t1 = *reinterpret_cast<const uint2*>(&s_tv[d][half * 8 + 4]);
    uint4 o; o.x = t0.x; o.y = t0.y; o.z = t1.x; o.w = t1.y;
    *reinterpret_cast<uint4*>(vt + (size_t)d * 8192 + row0 + half * 8) = o;
  }
}

// ---- online softmax for one 16-q half; THR=8 defer-max (exact bookkeeping) ----
__device__ __forceinline__ short8 sm_half(
    const f32x4& s0, const f32x4& s1, float& mrun, float& lrun,
    f32x4* __restrict__ oacc, uint_t* __restrict__ prow, int g)
{
  float t0 = fmaxf(fmaxf(fmaxf(s0[0], s0[1]), fmaxf(s0[2], s0[3])),
                   fmaxf(fmaxf(s1[0], s1[1]), fmaxf(s1[2], s1[3])));
  t0 = fmaxf(t0, __shfl_xor(t0, 16, 64));
  t0 = fmaxf(t0, __shfl_xor(t0, 32, 64));
  if (__any(t0 > mrun + 8.0f)){
    float mnew = fmaxf(mrun, t0);
    float fac  = exp2f(mrun - mnew);
    lrun *= fac;
    #pragma unroll
    for (int dt = 0; dt < 8; ++dt){
      oacc[dt][0] *= fac; oacc[dt][1] *= fac; oacc[dt][2] *= fac; oacc[dt][3] *= fac;
    }
    mrun = mnew;
  }
  float p00 = exp2f(s0[0] - mrun), p01 = exp2f(s0[1] - mrun);
  float p02 = exp2f(s0[2] - mrun), p03 = exp2f(s0[3] - mrun);
  float p10 = exp2f(s1[0] - mrun), p11 = exp2f(s1[1] - mrun);
  float p12 = exp2f(s1[2] - mrun), p13 = exp2f(s1[3] - mrun);
  float ps = ((p00 + p01) + (p02 + p03)) + ((p10 + p11) + (p12 + p13));
  ps += __shfl_xor(ps, 16, 64);
  ps += __shfl_xor(ps, 32, 64);
  lrun += ps;
  uint2 w0; w0.x = cvtpk(p00, p01); w0.y = cvtpk(p02, p03);
  uint2 w1; w1.x = cvtpk(p10, p11); w1.y = cvtpk(p12, p13);
  *reinterpret_cast<uint2*>(prow + 2 * g)     = w0;
  *reinterpret_cast<uint2*>(prow + 8 + 2 * g) = w1;
  return *reinterpret_cast<const short8*>(prow + 4 * g);
}

// ---- MFMA flash attention: 32 q/wave, KVBLK=64, s_setprio on MFMA clusters ----
// Round-18-proven structure; ONLY change: T5 setprio(1) around MFMA clusters
// (pure scheduler hint, no codegen surface).
// BANNED (NaN): reg-prefetch (r11/r12), LDS double-buffer (r16).
// BANNED (spill): launch_bounds waves/EU 4/6 (r14/r15); (256,3) is stable.
template<int NCH_T>
__global__ __launch_bounds__(256, 3) void attn_mfma(
    const ushort_t* __restrict__ qf, const ushort_t* __restrict__ kf, const ushort_t* __restrict__ vt,
    ushort_t* __restrict__ pacc, float* __restrict__ pm, float* __restrict__ pl)
{
  constexpr int CHUNK_T = 8192 / NCH_T;
  constexpr int TILES_T = CHUNK_T / 64;

  const int tid  = threadIdx.x;
  const int lane = tid & 63;
  const int w    = tid >> 6;
  const int g    = lane >> 4;
  const int hl   = lane & 15;
  const int qb   = blockIdx.x & 63;
  const int jc   = blockIdx.x >> 6;
  const int qw   = qb * 128 + w * 32;
  const int qrA  = qw + hl;
  const int qrB  = qw + 16 + hl;

  __shared__ ushort_t s_k[64][128];    // XOR-swizzled: col ^= (row&7)*8
  __shared__ ushort_t s_vt[128][64];   // XOR-swizzled: col ^= (row&7)*8
  __shared__ uint_t   s_p32[4][2][16][20];

  const int kjj0 = tid >> 4;            // 0..15, rows +i*16
  const int kkk  = (tid & 15) * 8;
  const int vd0  = tid >> 3;            // 0..31, rows +i*32
  const int vjo  = (tid & 7) * 8;
  const int jstart = jc * CHUNK_T;

  short8 qfA[4], qfB[4];
  #pragma unroll
  for (int kt = 0; kt < 4; ++kt){
    qfA[kt] = ld8(qf + (size_t)qrA * 128 + kt * 32 + g * 8);
    qfB[kt] = ld8(qf + (size_t)qrB * 128 + kt * 32 + g * 8);
  }

  f32x4 oA[8], oB[8];
  #pragma unroll
  for (int dt = 0; dt < 8; ++dt){
    oA[dt] = (f32x4){0.f, 0.f, 0.f, 0.f};
    oB[dt] = (f32x4){0.f, 0.f, 0.f, 0.f};
  }
  float mA = -3.0e38f, lA = 0.f, mB = -3.0e38f, lB = 0.f;

  for (int t = 0; t < TILES_T; ++t){
    const int jb = jstart + t * 64;
    __syncthreads();
    #pragma unroll
    for (int i = 0; i < 4; ++i){
      int kr = kjj0 + i * 16;
      *reinterpret_cast<uint4*>(&s_k[kr][kkk ^ ((kr & 7) * 8)]) =
          *reinterpret_cast<const uint4*>(kf + (size_t)(jb + kr) * 128 + kkk);
      int vr = vd0 + i * 32;
      *reinterpret_cast<uint4*>(&s_vt[vr][vjo ^ ((vr & 7) * 8)]) =
          *reinterpret_cast<const uint4*>(vt + (size_t)vr * 8192 + jb + vjo);
    }
    __syncthreads();

    #pragma unroll
    for (int sub = 0; sub < 2; ++sub){
      // ---- QK^T for both q-halves over 32-row subtile ----
      f32x4 sA[2], sB[2];
      __builtin_amdgcn_s_setprio(1);
      #pragma unroll
      for (int jt = 0; jt < 2; ++jt){
        sA[jt] = (f32x4){0.f, 0.f, 0.f, 0.f};
        sB[jt] = (f32x4){0.f, 0.f, 0.f, 0.f};
        #pragma unroll
        for (int kt = 0; kt < 4; ++kt){
          short8 kfr = ld8(&s_k[sub * 32 + jt * 16 + hl][(kt * 32 + g * 8) ^ ((hl & 7) * 8)]);
          sA[jt] = __builtin_amdgcn_mfma_f32_16x16x32_bf16(kfr, qfA[kt], sA[jt], 0, 0, 0);
          sB[jt] = __builtin_amdgcn_mfma_f32_16x16x32_bf16(kfr, qfB[kt], sB[jt], 0, 0, 0);
        }
      }
      __builtin_amdgcn_s_setprio(0);

      short8 pfA = sm_half(sA[0], sA[1], mA, lA, oA, &s_p32[w][0][hl][0], g);
      short8 pfB = sm_half(sB[0], sB[1], mB, lB, oB, &s_p32[w][1][hl][0], g);

      // ---- PV for both halves ----
      __builtin_amdgcn_s_setprio(1);
      #pragma unroll
      for (int dt = 0; dt < 8; ++dt){
        short8 vfr = ld8(&s_vt[dt * 16 + hl][(sub * 32 + g * 8) ^ ((hl & 7) * 8)]);
        oA[dt] = __builtin_amdgcn_mfma_f32_16x16x32_bf16(vfr, pfA, oA[dt], 0, 0, 0);
        oB[dt] = __builtin_amdgcn_mfma_f32_16x16x32_bf16(vfr, pfB, oB[dt], 0, 0, 0);
      }
      __builtin_amdgcn_s_setprio(0);
    }
  }

  // ---- write partials (bf16, pair-packed 8B stores) ----
  #pragma unroll
  for (int dt = 0; dt < 8; ++dt){
    uint2 a;
    a.x = cvtpk(oA[dt][0], oA[dt][1]);
    a.y = cvtpk(oA[dt][2], oA[dt][3]);
    *reinterpret_cast<uint2*>(pacc + ((size_t)jc * 8192 + qrA) * 128 + dt * 16 + 4 * g) = a;
    uint2 b;
    b.x = cvtpk(oB[dt][0], oB[dt][1]);
    b.y = cvtpk(oB[dt][2], oB[dt][3]);
    *reinterpret_cast<uint2*>(pacc + ((size_t)jc * 8192 + qrB) * 128 + dt * 16 + 4 * g) = b;
  }
  if (g == 0){
    pm[jc * 8192 + qrA] = mA;  pl[jc * 8192 + qrA] = lA;
    pm[jc * 8192 + qrB] = mB;  pl[jc * 8192 + qrB] = lB;
  }
}

// ---- combine chunk partials + residual + halt/stack heads ----
template<int NCH_T>
__global__ __launch_bounds__(256, 1) void combine_kernel(
    const ushort_t* __restrict__ pacc, const float* __restrict__ pm, const float* __restrict__ pl,
    const float* __restrict__ resb,
    const float* __restrict__ halt_W, const float* __restrict__ halt_b,
    const float* __restrict__ stack_W, const float* __restrict__ stack_b,
    float* __restrict__ out)
{
  const int tid  = threadIdx.x;
  const int lane = tid & 63;
  const int w    = tid >> 6;
  const int q    = blockIdx.x * 4 + w;

  float mv[NCH_T], M = -3.0e38f;
  #pragma unroll
  for (int c = 0; c < NCH_T; ++c){ mv[c] = pm[c * 8192 + q]; M = fmaxf(M, mv[c]); }
  float f[NCH_T]; float L = 0.f;
  #pragma unroll
  for (int c = 0; c < NCH_T; ++c){ f[c] = exp2f(mv[c] - M); L += pl[c * 8192 + q] * f[c]; }
  float invL = 1.0f / L;

  float o0 = 0.f, o1 = 0.f;
  #pragma unroll
  for (int c = 0; c < NCH_T; ++c){
    const ushort_t* pa = pacc + ((size_t)c * 8192 + q) * 128;
    o0 += bf2f(pa[lane])      * f[c];
    o1 += bf2f(pa[64 + lane]) * f[c];
  }
  o0 = o0 * invL + resb[(size_t)q * 128 + lane];
  o1 = o1 * invL + resb[(size_t)q * 128 + 64 + lane];
  out[(size_t)q * 64 + lane] = o0;
  out[(size_t)8192 * 64 + (size_t)q * 64 + lane] = o1;

  float ssq  = wave_sum64(o0 * o0 + o1 * o1);
  float invn = 1.0f / (sqrtf(ssq) + 1e-6f);
  float zn0 = o0 * invn, zn1 = o1 * invn;
  float hp = wave_sum64(zn0 * halt_W[lane]        + zn1 * halt_W[64 + lane]);
  float s0 = wave_sum64(zn0 * stack_W[lane]       + zn1 * stack_W[64 + lane]);
  float s1 = wave_sum64(zn0 * stack_W[128 + lane] + zn1 * stack_W[192 + lane]);
  float s2 = wave_sum64(zn0 * stack_W[256 + lane] + zn1 * stack_W[320 + lane]);
  if (lane == 0){
    out[1048576 + q] = hp + halt_b[0];
    out[1056768 + (size_t)q * 3 + 0] = s0 + stack_b[0];
    out[1056768 + (size_t)q * 3 + 1] = s1 + stack_b[1];
    out[1056768 + (size_t)q * 3 + 2] = s2 + stack_b[2];
  }
}

extern "C" void kernel_launch(void* const* d_in, const int* in_sizes, int n_in,
                              void* d_out, int out_size, void* d_ws, size_t ws_size,
                              hipStream_t stream){
  const float* z_real  = (const float*)d_in[0];
  const float* z_imag  = (const float*)d_in[1];
  const float* gate_W  = (const float*)d_in[2];
  const float* gate_b  = (const float*)d_in[3];
  const float* exp_Wr  = (const float*)d_in[4];
  const float* exp_Wi  = (const float*)d_in[5];
  const float* ln_scale= (const float*)d_in[6];
  const float* ln_shift= (const float*)d_in[7];
  const float* mod_bias= (const float*)d_in[8];
  const float* q_Wr    = (const float*)d_in[9];
  const float* q_Wi    = (const float*)d_in[10];
  const float* k_Wr    = (const float*)d_in[11];
  const float* k_Wi    = (const float*)d_in[12];
  const float* v_Wr    = (const float*)d_in[13];
  const float* v_Wi    = (const float*)d_in[14];
  const float* ctx_W   = (const float*)d_in[15];
  const float* ctx_b   = (const float*)d_in[16];
  const float* res_W   = (const float*)d_in[17];
  const float* res_b   = (const float*)d_in[18];
  const float* halt_W  = (const float*)d_in[19];
  const float* halt_b  = (const float*)d_in[20];
  const float* stack_W = (const float*)d_in[21];
  const float* stack_b = (const float*)d_in[22];

  auto need = [&](int nch)->size_t{
    size_t b = (size_t)3 * 8192 * 128 * 2;                       // qbf,kbf,vtb bf16
    b += (size_t)8192 * 128 * 4;                                 // resb fp32
    b += (size_t)nch * 8192 * 128 * 2;                           // pacc bf16
    b += (size_t)2 * nch * 8192 * 4;                             // pm, pl
    b += (size_t)2 * WTOT * 2;                                   // whi, wlo
    return b;
  };
  const int nch = (ws_size >= need(16)) ? 16 : 8;

  ushort_t* qbf = (ushort_t*)d_ws;
  ushort_t* kbf = qbf + (size_t)8192*128;
  ushort_t* vtb = kbf + (size_t)8192*128;
  float* resb = (float*)(vtb + (size_t)8192*128);
  ushort_t* pacc = (ushort_t*)(resb + (size_t)8192*128);
  float* pm   = (float*)(pacc + (size_t)nch*8192*128);
  float* pl   = pm   + (size_t)nch*8192;
  ushort_t* whi = (ushort_t*)(pl + (size_t)nch*8192);
  ushort_t* wlo = whi + WTOT;

  wconv_kernel<<<(WTOT + 255) / 256, 256, 0, stream>>>(gate_W, exp_Wr, exp_Wi,
      q_Wr, q_Wi, k_Wr, k_Wi, v_Wr, v_Wi, ctx_W, res_W, whi, wlo);
  prep_kernel<<<512, 256, 0, stream>>>(z_real, z_imag, whi, wlo, gate_b,
      ln_scale, ln_shift, mod_bias, ctx_b, res_b, qbf, kbf, vtb, resb);
  if (nch == 16){
    attn_mfma<16><<<64*16, 256, 0, stream>>>(qbf, kbf, vtb, pacc, pm, pl);
    combine_kernel<16><<<2048, 256, 0, stream>>>(pacc, pm, pl, resb,
        halt_W, halt_b, stack_W, stack_b, (float*)d_out);
  } else {
    attn_mfma<8><<<64*8, 256, 0, stream>>>(qbf, kbf, vtb, pacc, pm, pl);
    combine_kernel<8><<<2048, 256, 0, stream>>>(pacc, pm, pl, resb,
        halt_W, halt_b, stack_W, stack_b, (float*)d_out);
  }
}

// Round 20
// 102.635 us; speedup vs baseline: 4.4621x; 1.0101x over previous
//
#include <hip/hip_runtime.h>
#include <math.h>

#define EPS_F 1e-6f
#define QSC   (0.125f * 1.44269504088896340736f)   // ATTN_SCALE * log2(e)

// weight-buffer offsets (elements) in whi/wlo
#define GATE_O 0
#define EWR_O  512
#define EWI_O  16896
#define QWR_O  33280
#define QWI_O  37376
#define KWR_O  41472
#define KWI_O  45568
#define VWR_O  49664
#define VWI_O  53760
#define CTX_O  57856
#define RES_O  74240
#define WTOT   90624

typedef __attribute__((ext_vector_type(8))) short short8;
typedef __attribute__((ext_vector_type(4))) float f32x4;
typedef unsigned short ushort_t;
typedef unsigned int uint_t;

__device__ __forceinline__ ushort_t f2bf(float x){
  uint_t u = __float_as_uint(x);
  u += 0x7fffu + ((u >> 16) & 1u);
  return (ushort_t)(u >> 16);
}
__device__ __forceinline__ float bf2f(ushort_t u){
  return __uint_as_float(((uint_t)u) << 16);
}
// hardware packed f32->bf16 (RNE), 1 inst for 2 values
__device__ __forceinline__ uint_t cvtpk(float lo, float hi){
  uint_t r;
  asm("v_cvt_pk_bf16_f32 %0, %1, %2" : "=v"(r) : "v"(lo), "v"(hi));
  return r;
}

__device__ __forceinline__ float wave_sum64(float v){
  #pragma unroll
  for (int m = 32; m > 0; m >>= 1) v += __shfl_xor(v, m, 64);
  return v;
}
__device__ __forceinline__ float qsum16(float v){
  #pragma unroll
  for (int m = 1; m < 16; m <<= 1) v += __shfl_xor(v, m, 64);
  return v;
}

__device__ __forceinline__ short8 neg8(short8 v){
  uint4 u = *reinterpret_cast<uint4*>(&v);
  u.x ^= 0x80008000u; u.y ^= 0x80008000u; u.z ^= 0x80008000u; u.w ^= 0x80008000u;
  return *reinterpret_cast<short8*>(&u);
}
__device__ __forceinline__ short8 ld8(const ushort_t* __restrict__ p){
  return *reinterpret_cast<const short8*>(p);
}

#define MFMA(a,b,c) __builtin_amdgcn_mfma_f32_16x16x32_bf16((a),(b),(c),0,0,0)

// ============ weight conversion: fp32 -> bf16 hi/lo, fragment-ready ============
__global__ __launch_bounds__(256) void wconv_kernel(
    const float* __restrict__ gate_W, const float* __restrict__ exp_Wr,
    const float* __restrict__ exp_Wi,
    const float* __restrict__ q_Wr, const float* __restrict__ q_Wi,
    const float* __restrict__ k_Wr, const float* __restrict__ k_Wi,
    const float* __restrict__ v_Wr, const float* __restrict__ v_Wi,
    const float* __restrict__ ctx_W, const float* __restrict__ res_W,
    ushort_t* __restrict__ whi, ushort_t* __restrict__ wlo)
{
  int i = blockIdx.x * 256 + threadIdx.x;
  if (i >= WTOT) return;
  float v;
  if      (i < EWR_O) v = gate_W[i - GATE_O];
  else if (i < EWI_O) v = exp_Wr[i - EWR_O];
  else if (i < QWR_O) v = exp_Wi[i - EWI_O];
  else if (i < QWI_O) v = q_Wr[i - QWR_O];
  else if (i < KWR_O) v = q_Wi[i - QWI_O];
  else if (i < KWI_O) v = k_Wr[i - KWR_O];
  else if (i < VWR_O) v = k_Wi[i - KWI_O];
  else if (i < VWI_O) v = v_Wr[i - VWR_O];
  else if (i < CTX_O) v = v_Wi[i - VWI_O];
  else if (i < RES_O) v = ctx_W[i - CTX_O];
  else                v = res_W[i - RES_O];
  ushort_t h = f2bf(v);
  whi[i] = h;
  wlo[i] = f2bf(v - bf2f(h));
}

// ============ prep v3: MFMA everywhere, 4 waves/block, wave = col-tile ============
__global__ __launch_bounds__(256, 4) void prep_kernel(
    const float* __restrict__ z_real, const float* __restrict__ z_imag,
    const ushort_t* __restrict__ whi, const ushort_t* __restrict__ wlo,
    const float* __restrict__ gate_b,
    const float* __restrict__ ln_scale, const float* __restrict__ ln_shift,
    const float* __restrict__ mod_bias,
    const float* __restrict__ ctx_b, const float* __restrict__ res_b,
    ushort_t* __restrict__ qf, ushort_t* __restrict__ kf, ushort_t* __restrict__ vt,
    float* __restrict__ resb)
{
  const int tid  = threadIdx.x;
  const int lane = tid & 63;
  const int w    = tid >> 6;
  const int g    = lane >> 4;
  const int c    = lane & 15;
  const int row0 = blockIdx.x * 16;
  const int col  = w * 16 + c;
  const f32x4 z4 = {0.f, 0.f, 0.f, 0.f};

  __shared__ ushort_t s_xh[16][136];
  __shared__ ushort_t s_xl[16][136];
  __shared__ ushort_t s_a [16][136];
  __shared__ ushort_t s_tv[128][20];
  __shared__ float    s_red[4][16][2];

  {
    int rowl = tid >> 4;
    int col0 = (tid & 15) * 8;
    const float* src = (col0 < 64) ? (z_real + (size_t)(row0 + rowl) * 64 + col0)
                                   : (z_imag + (size_t)(row0 + rowl) * 64 + (col0 - 64));
    float4 a = *reinterpret_cast<const float4*>(src);
    float4 b = *reinterpret_cast<const float4*>(src + 4);
    float f[8] = {a.x, a.y, a.z, a.w, b.x, b.y, b.z, b.w};
    uint_t hp[4], lp[4];
    #pragma unroll
    for (int e = 0; e < 4; ++e){
      ushort_t h0 = f2bf(f[2*e]), h1 = f2bf(f[2*e+1]);
      hp[e] = (uint_t)h0 | ((uint_t)h1 << 16);
      lp[e] = (uint_t)f2bf(f[2*e]   - bf2f(h0)) |
              ((uint_t)f2bf(f[2*e+1] - bf2f(h1)) << 16);
    }
    uint4 uh; uh.x = hp[0]; uh.y = hp[1]; uh.z = hp[2]; uh.w = hp[3];
    uint4 ul; ul.x = lp[0]; ul.y = lp[1]; ul.z = lp[2]; ul.w = lp[3];
    *reinterpret_cast<uint4*>(&s_xh[rowl][col0]) = uh;
    *reinterpret_cast<uint4*>(&s_xl[rowl][col0]) = ul;
  }
  __syncthreads();

  short8 xh[4], xl[4];
  #pragma unroll
  for (int ks = 0; ks < 4; ++ks){
    xh[ks] = ld8(&s_xh[c][ks * 32 + g * 8]);
    xl[ks] = ld8(&s_xl[c][ks * 32 + g * 8]);
  }

  // ---- gate (compensated) ----
  float gwv[4];
  {
    f32x4 ga = z4;
    #pragma unroll
    for (int ks = 0; ks < 4; ++ks){
      int off = GATE_O + (c & 3) * 128 + ks * 32 + g * 8;
      short8 wh = ld8(whi + off), wl = ld8(wlo + off);
      ga = MFMA(xh[ks], wh, ga);
      ga = MFMA(xl[ks], wh, ga);
      ga = MFMA(xh[ks], wl, ga);
    }
    float gb = gate_b[c & 3];
    #pragma unroll
    for (int r = 0; r < 4; ++r){
      float le = ga[r] + gb;
      float mx = fmaxf(le, __shfl_xor(le, 1, 64));
      mx = fmaxf(mx, __shfl_xor(mx, 2, 64));
      float ev = __expf(le - mx);
      float sm = ev + __shfl_xor(ev, 1, 64);
      sm += __shfl_xor(sm, 2, 64);
      gwv[r] = ev / sm;
    }
  }

  // ---- MoE (compensated) ----
  f32x4 mrr = z4, mri = z4;
  #pragma unroll
  for (int e = 0; e < 4; ++e){
    float gwr[4];
    #pragma unroll
    for (int r = 0; r < 4; ++r) gwr[r] = __shfl(gwv[r], g * 16 + e, 64);
    f32x4 er = z4, ei = z4;
    #pragma unroll
    for (int ks = 0; ks < 2; ++ks){
      int boff = e * 4096 + col * 64 + ks * 32 + g * 8;
      short8 wrh = ld8(whi + EWR_O + boff);
      short8 wrl = ld8(wlo + EWR_O + boff);
      short8 wih = ld8(whi + EWI_O + boff);
      short8 wil = ld8(wlo + EWI_O + boff);
      short8 wihn = neg8(wih), wiln = neg8(wil);
      er = MFMA(xh[ks],   wrh, er);   ei = MFMA(xh[ks+2], wrh, ei);
      er = MFMA(xl[ks],   wrh, er);   ei = MFMA(xl[ks+2], wrh, ei);
      er = MFMA(xh[ks],   wrl, er);   ei = MFMA(xh[ks+2], wrl, ei);
      er = MFMA(xh[ks+2], wihn, er);  ei = MFMA(xh[ks],   wih, ei);
      er = MFMA(xl[ks+2], wihn, er);  ei = MFMA(xl[ks],   wih, ei);
      er = MFMA(xh[ks+2], wiln, er);  ei = MFMA(xh[ks],   wil, ei);
    }
    #pragma unroll
    for (int r = 0; r < 4; ++r){
      mrr[r] = fmaf(gwr[r], er[r], mrr[r]);
      mri[r] = fmaf(gwr[r], ei[r], mri[r]);
    }
  }

  // ---- ComplexLayerNorm (ddof=1) + ModReLU ----
  {
    float hh[4], mg[4];
    #pragma unroll
    for (int r = 0; r < 4; ++r){
      hh[r] = sqrtf(mrr[r] * mrr[r] + mri[r] * mri[r]);
      mg[r] = hh[r] + EPS_F;
    }
    #pragma unroll
    for (int r = 0; r < 4; ++r){
      float sx  = qsum16(mg[r]);
      float sxx = qsum16(mg[r] * mg[r]);
      if (c == 0){ s_red[w][g * 4 + r][0] = sx; s_red[w][g * 4 + r][1] = sxx; }
    }
    __syncthreads();
    float lsc = ln_scale[col], lsh = ln_shift[col], mb = mod_bias[col];
    #pragma unroll
    for (int r = 0; r < 4; ++r){
      int rr = g * 4 + r;
      float SX  = s_red[0][rr][0] + s_red[1][rr][0] + s_red[2][rr][0] + s_red[3][rr][0];
      float SXX = s_red[0][rr][1] + s_red[1][rr][1] + s_red[2][rr][1] + s_red[3][rr][1];
      float mean = SX * (1.0f / 64.0f);
      float var  = (SXX - SX * mean) * (1.0f / 63.0f);
      float istd = rsqrtf(var + EPS_F);
      float nm = (mg[r] - mean) * istd * lsc + lsh;
      float lr, li;
      if (hh[r] > 0.f){ float ih = 1.0f / hh[r]; lr = nm * mrr[r] * ih; li = nm * mri[r] * ih; }
      else            { lr = nm; li = 0.f; }
      float nrm = sqrtf(lr * lr + li * li) + EPS_F;
      float sf  = fmaxf(nrm + mb, 0.f) / nrm;
      s_a[rr][col]      = f2bf(lr * sf);
      s_a[rr][64 + col] = f2bf(li * sf);
    }
  }
  __syncthreads();

  // ---- ctx gate ----
  f32x4 cwa[2];
  #pragma unroll
  for (int ii = 0; ii < 2; ++ii){
    int ct8 = w + ii * 4;
    f32x4 a = z4;
    #pragma unroll
    for (int ks = 0; ks < 4; ++ks)
      a = MFMA(xh[ks], ld8(whi + CTX_O + (ct8 * 16 + c) * 128 + ks * 32 + g * 8), a);
    float cb = ctx_b[ct8 * 16 + c];
    #pragma unroll
    for (int r = 0; r < 4; ++r) cwa[ii][r] = 1.0f / (1.0f + __expf(-(a[r] + cb)));
  }

  // ---- residual ----
  #pragma unroll
  for (int ii = 0; ii < 2; ++ii){
    int ct8 = w + ii * 4;
    f32x4 a = z4;
    #pragma unroll
    for (int ks = 0; ks < 4; ++ks)
      a = MFMA(xh[ks], ld8(whi + RES_O + (ct8 * 16 + c) * 128 + ks * 32 + g * 8), a);
    float rb = res_b[ct8 * 16 + c];
    #pragma unroll
    for (int r = 0; r < 4; ++r)
      resb[(size_t)(row0 + 4 * g + r) * 128 + ct8 * 16 + c] = 0.1f * (a[r] + rb);
  }

  // ---- QKV ----
  short8 ar_[2], ai_[2], ain_[2];
  #pragma unroll
  for (int ks = 0; ks < 2; ++ks){
    ar_[ks]  = ld8(&s_a[c][ks * 32 + g * 8]);
    ai_[ks]  = ld8(&s_a[c][64 + ks * 32 + g * 8]);
    ain_[ks] = neg8(ai_[ks]);
  }

  #pragma unroll
  for (int mat = 0; mat < 3; ++mat){
    int roff = (mat == 0) ? QWR_O : (mat == 1) ? KWR_O : VWR_O;
    int ioff = (mat == 0) ? QWI_O : (mat == 1) ? KWI_O : VWI_O;
    f32x4 orr = z4, oii = z4;
    #pragma unroll
    for (int ks = 0; ks < 2; ++ks){
      int boff = col * 64 + ks * 32 + g * 8;
      short8 wrh = ld8(whi + roff + boff);
      short8 wrl = ld8(wlo + roff + boff);
      short8 wih = ld8(whi + ioff + boff);
      short8 wil = ld8(wlo + ioff + boff);
      orr = MFMA(ar_[ks],  wrh, orr);  oii = MFMA(ai_[ks], wrh, oii);
      orr = MFMA(ar_[ks],  wrl, orr);  oii = MFMA(ai_[ks], wrl, oii);
      orr = MFMA(ain_[ks], wih, orr);  oii = MFMA(ar_[ks], wih, oii);
      orr = MFMA(ain_[ks], wil, orr);  oii = MFMA(ar_[ks], wil, oii);
    }
    if (mat == 0){
      #pragma unroll
      for (int r = 0; r < 4; ++r){
        size_t row = row0 + 4 * g + r;
        qf[row * 128 + col]      = f2bf(orr[r] * cwa[0][r] * QSC);
        qf[row * 128 + 64 + col] = f2bf(oii[r] * cwa[1][r] * QSC);
      }
    } else if (mat == 1){
      #pragma unroll
      for (int r = 0; r < 4; ++r){
        size_t row = row0 + 4 * g + r;
        kf[row * 128 + col]      = f2bf(orr[r]);
        kf[row * 128 + 64 + col] = f2bf(oii[r]);
      }
    } else {
      #pragma unroll
      for (int r = 0; r < 4; ++r){
        s_tv[col][4 * g + r]      = f2bf(orr[r]);
        s_tv[64 + col][4 * g + r] = f2bf(oii[r]);
      }
    }
  }
  __syncthreads();

  {
    int d = tid >> 1, half = tid & 1;
    uint2 t0 = *reinterpret_cast<const uint2*>(&s_tv[d][half * 8]);
    uint2 t1 = *reinterpret_cast<const uint2*>(&s_tv[d][half * 8 + 4]);
    uint4 o; o.x = t0.x; o.y = t0.y; o.z = t1.x; o.w = t1.y;
    *reinterpret_cast<uint4*>(vt + (size_t)d * 8192 + row0 + half * 8) = o;
  }
}

// ---- online softmax for one 16-q half; THR=8 defer-max (exact bookkeeping) ----
__device__ __forceinline__ short8 sm_half(
    const f32x4& s0, const f32x4& s1, float& mrun, float& lrun,
    f32x4* __restrict__ oacc, uint_t* __restrict__ prow, int g)
{
  float t0 = fmaxf(fmaxf(fmaxf(s0[0], s0[1]), fmaxf(s0[2], s0[3])),
                   fmaxf(fmaxf(s1[0], s1[1]), fmaxf(s1[2], s1[3])));
  t0 = fmaxf(t0, __shfl_xor(t0, 16, 64));
  t0 = fmaxf(t0, __shfl_xor(t0, 32, 64));
  if (__any(t0 > mrun + 8.0f)){
    float mnew = fmaxf(mrun, t0);
    float fac  = exp2f(mrun - mnew);
    lrun *= fac;
    #pragma unroll
    for (int dt = 0; dt < 8; ++dt){
      oacc[dt][0] *= fac; oacc[dt][1] *= fac; oacc[dt][2] *= fac; oacc[dt][3] *= fac;
    }
    mrun = mnew;
  }
  float p00 = exp2f(s0[0] - mrun), p01 = exp2f(s0[1] - mrun);
  float p02 = exp2f(s0[2] - mrun), p03 = exp2f(s0[3] - mrun);
  float p10 = exp2f(s1[0] - mrun), p11 = exp2f(s1[1] - mrun);
  float p12 = exp2f(s1[2] - mrun), p13 = exp2f(s1[3] - mrun);
  float ps = ((p00 + p01) + (p02 + p03)) + ((p10 + p11) + (p12 + p13));
  ps += __shfl_xor(ps, 16, 64);
  ps += __shfl_xor(ps, 32, 64);
  lrun += ps;
  uint2 w0; w0.x = cvtpk(p00, p01); w0.y = cvtpk(p02, p03);
  uint2 w1; w1.x = cvtpk(p10, p11); w1.y = cvtpk(p12, p13);
  *reinterpret_cast<uint2*>(prow + 2 * g)     = w0;
  *reinterpret_cast<uint2*>(prow + 8 + 2 * g) = w1;
  return *reinterpret_cast<const short8*>(prow + 4 * g);
}

// ---- MFMA flash attention: 32 q/wave, KVBLK=64, s_setprio on MFMA clusters ----
// Round-19-proven structure, byte-identical.
// BANNED (NaN): reg-prefetch (r11/r12), LDS double-buffer (r16).
// BANNED (spill): launch_bounds waves/EU 4/6 (r14/r15); (256,3) is stable.
template<int NCH_T>
__global__ __launch_bounds__(256, 3) void attn_mfma(
    const ushort_t* __restrict__ qf, const ushort_t* __restrict__ kf, const ushort_t* __restrict__ vt,
    ushort_t* __restrict__ pacc, float* __restrict__ pm, float* __restrict__ pl)
{
  constexpr int CHUNK_T = 8192 / NCH_T;
  constexpr int TILES_T = CHUNK_T / 64;

  const int tid  = threadIdx.x;
  const int lane = tid & 63;
  const int w    = tid >> 6;
  const int g    = lane >> 4;
  const int hl   = lane & 15;
  const int qb   = blockIdx.x & 63;
  const int jc   = blockIdx.x >> 6;
  const int qw   = qb * 128 + w * 32;
  const int qrA  = qw + hl;
  const int qrB  = qw + 16 + hl;

  __shared__ ushort_t s_k[64][128];    // XOR-swizzled: col ^= (row&7)*8
  __shared__ ushort_t s_vt[128][64];   // XOR-swizzled: col ^= (row&7)*8
  __shared__ uint_t   s_p32[4][2][16][20];

  const int kjj0 = tid >> 4;            // 0..15, rows +i*16
  const int kkk  = (tid & 15) * 8;
  const int vd0  = tid >> 3;            // 0..31, rows +i*32
  const int vjo  = (tid & 7) * 8;
  const int jstart = jc * CHUNK_T;

  short8 qfA[4], qfB[4];
  #pragma unroll
  for (int kt = 0; kt < 4; ++kt){
    qfA[kt] = ld8(qf + (size_t)qrA * 128 + kt * 32 + g * 8);
    qfB[kt] = ld8(qf + (size_t)qrB * 128 + kt * 32 + g * 8);
  }

  f32x4 oA[8], oB[8];
  #pragma unroll
  for (int dt = 0; dt < 8; ++dt){
    oA[dt] = (f32x4){0.f, 0.f, 0.f, 0.f};
    oB[dt] = (f32x4){0.f, 0.f, 0.f, 0.f};
  }
  float mA = -3.0e38f, lA = 0.f, mB = -3.0e38f, lB = 0.f;

  for (int t = 0; t < TILES_T; ++t){
    const int jb = jstart + t * 64;
    __syncthreads();
    #pragma unroll
    for (int i = 0; i < 4; ++i){
      int kr = kjj0 + i * 16;
      *reinterpret_cast<uint4*>(&s_k[kr][kkk ^ ((kr & 7) * 8)]) =
          *reinterpret_cast<const uint4*>(kf + (size_t)(jb + kr) * 128 + kkk);
      int vr = vd0 + i * 32;
      *reinterpret_cast<uint4*>(&s_vt[vr][vjo ^ ((vr & 7) * 8)]) =
          *reinterpret_cast<const uint4*>(vt + (size_t)vr * 8192 + jb + vjo);
    }
    __syncthreads();

    #pragma unroll
    for (int sub = 0; sub < 2; ++sub){
      // ---- QK^T for both q-halves over 32-row subtile ----
      f32x4 sA[2], sB[2];
      __builtin_amdgcn_s_setprio(1);
      #pragma unroll
      for (int jt = 0; jt < 2; ++jt){
        sA[jt] = (f32x4){0.f, 0.f, 0.f, 0.f};
        sB[jt] = (f32x4){0.f, 0.f, 0.f, 0.f};
        #pragma unroll
        for (int kt = 0; kt < 4; ++kt){
          short8 kfr = ld8(&s_k[sub * 32 + jt * 16 + hl][(kt * 32 + g * 8) ^ ((hl & 7) * 8)]);
          sA[jt] = __builtin_amdgcn_mfma_f32_16x16x32_bf16(kfr, qfA[kt], sA[jt], 0, 0, 0);
          sB[jt] = __builtin_amdgcn_mfma_f32_16x16x32_bf16(kfr, qfB[kt], sB[jt], 0, 0, 0);
        }
      }
      __builtin_amdgcn_s_setprio(0);

      short8 pfA = sm_half(sA[0], sA[1], mA, lA, oA, &s_p32[w][0][hl][0], g);
      short8 pfB = sm_half(sB[0], sB[1], mB, lB, oB, &s_p32[w][1][hl][0], g);

      // ---- PV for both halves ----
      __builtin_amdgcn_s_setprio(1);
      #pragma unroll
      for (int dt = 0; dt < 8; ++dt){
        short8 vfr = ld8(&s_vt[dt * 16 + hl][(sub * 32 + g * 8) ^ ((hl & 7) * 8)]);
        oA[dt] = __builtin_amdgcn_mfma_f32_16x16x32_bf16(vfr, pfA, oA[dt], 0, 0, 0);
        oB[dt] = __builtin_amdgcn_mfma_f32_16x16x32_bf16(vfr, pfB, oB[dt], 0, 0, 0);
      }
      __builtin_amdgcn_s_setprio(0);
    }
  }

  // ---- write partials (bf16, pair-packed 8B stores) ----
  #pragma unroll
  for (int dt = 0; dt < 8; ++dt){
    uint2 a;
    a.x = cvtpk(oA[dt][0], oA[dt][1]);
    a.y = cvtpk(oA[dt][2], oA[dt][3]);
    *reinterpret_cast<uint2*>(pacc + ((size_t)jc * 8192 + qrA) * 128 + dt * 16 + 4 * g) = a;
    uint2 b;
    b.x = cvtpk(oB[dt][0], oB[dt][1]);
    b.y = cvtpk(oB[dt][2], oB[dt][3]);
    *reinterpret_cast<uint2*>(pacc + ((size_t)jc * 8192 + qrB) * 128 + dt * 16 + 4 * g) = b;
  }
  if (g == 0){
    pm[jc * 8192 + qrA] = mA;  pl[jc * 8192 + qrA] = lA;
    pm[jc * 8192 + qrB] = mB;  pl[jc * 8192 + qrB] = lB;
  }
}

// ---- combine: VECTORIZED (lane owns dim pair 2l,2l+1; uint/float2 loads) ----
template<int NCH_T>
__global__ __launch_bounds__(256, 1) void combine_kernel(
    const ushort_t* __restrict__ pacc, const float* __restrict__ pm, const float* __restrict__ pl,
    const float* __restrict__ resb,
    const float* __restrict__ halt_W, const float* __restrict__ halt_b,
    const float* __restrict__ stack_W, const float* __restrict__ stack_b,
    float* __restrict__ out)
{
  const int tid  = threadIdx.x;
  const int lane = tid & 63;
  const int w    = tid >> 6;
  const int q    = blockIdx.x * 4 + w;
  const int d0   = lane * 2;           // this lane's output dims: d0, d0+1

  float mv[NCH_T], M = -3.0e38f;
  #pragma unroll
  for (int c = 0; c < NCH_T; ++c){ mv[c] = pm[c * 8192 + q]; M = fmaxf(M, mv[c]); }
  float f[NCH_T]; float L = 0.f;
  #pragma unroll
  for (int c = 0; c < NCH_T; ++c){ f[c] = exp2f(mv[c] - M); L += pl[c * 8192 + q] * f[c]; }
  float invL = 1.0f / L;

  float o0 = 0.f, o1 = 0.f;
  #pragma unroll
  for (int c = 0; c < NCH_T; ++c){
    uint_t pp = *reinterpret_cast<const uint_t*>(pacc + ((size_t)c * 8192 + q) * 128 + d0);
    o0 += bf2f((ushort_t)(pp & 0xffffu)) * f[c];
    o1 += bf2f((ushort_t)(pp >> 16))     * f[c];
  }
  float2 rb = *reinterpret_cast<const float2*>(resb + (size_t)q * 128 + d0);
  o0 = o0 * invL + rb.x;
  o1 = o1 * invL + rb.y;

  float2 ov; ov.x = o0; ov.y = o1;
  if (d0 < 64)
    *reinterpret_cast<float2*>(out + (size_t)q * 64 + d0) = ov;               // pr
  else
    *reinterpret_cast<float2*>(out + (size_t)8192 * 64 + (size_t)q * 64 + (d0 - 64)) = ov;  // pi

  float ssq  = wave_sum64(o0 * o0 + o1 * o1);
  float invn = 1.0f / (sqrtf(ssq) + 1e-6f);
  float zn0 = o0 * invn, zn1 = o1 * invn;
  float2 hw  = *reinterpret_cast<const float2*>(halt_W + d0);
  float2 s0w = *reinterpret_cast<const float2*>(stack_W + d0);
  float2 s1w = *reinterpret_cast<const float2*>(stack_W + 128 + d0);
  float2 s2w = *reinterpret_cast<const float2*>(stack_W + 256 + d0);
  float hp = wave_sum64(zn0 * hw.x  + zn1 * hw.y);
  float s0 = wave_sum64(zn0 * s0w.x + zn1 * s0w.y);
  float s1 = wave_sum64(zn0 * s1w.x + zn1 * s1w.y);
  float s2 = wave_sum64(zn0 * s2w.x + zn1 * s2w.y);
  if (lane == 0){
    out[1048576 + q] = hp + halt_b[0];
    out[1056768 + (size_t)q * 3 + 0] = s0 + stack_b[0];
    out[1056768 + (size_t)q * 3 + 1] = s1 + stack_b[1];
    out[1056768 + (size_t)q * 3 + 2] = s2 + stack_b[2];
  }
}

extern "C" void kernel_launch(void* const* d_in, const int* in_sizes, int n_in,
                              void* d_out, int out_size, void* d_ws, size_t ws_size,
                              hipStream_t stream){
  const float* z_real  = (const float*)d_in[0];
  const float* z_imag  = (const float*)d_in[1];
  const float* gate_W  = (const float*)d_in[2];
  const float* gate_b  = (const float*)d_in[3];
  const float* exp_Wr  = (const float*)d_in[4];
  const float* exp_Wi  = (const float*)d_in[5];
  const float* ln_scale= (const float*)d_in[6];
  const float* ln_shift= (const float*)d_in[7];
  const float* mod_bias= (const float*)d_in[8];
  const float* q_Wr    = (const float*)d_in[9];
  const float* q_Wi    = (const float*)d_in[10];
  const float* k_Wr    = (const float*)d_in[11];
  const float* k_Wi    = (const float*)d_in[12];
  const float* v_Wr    = (const float*)d_in[13];
  const float* v_Wi    = (const float*)d_in[14];
  const float* ctx_W   = (const float*)d_in[15];
  const float* ctx_b   = (const float*)d_in[16];
  const float* res_W   = (const float*)d_in[17];
  const float* res_b   = (const float*)d_in[18];
  const float* halt_W  = (const float*)d_in[19];
  const float* halt_b  = (const float*)d_in[20];
  const float* stack_W = (const float*)d_in[21];
  const float* stack_b = (const float*)d_in[22];

  auto need = [&](int nch)->size_t{
    size_t b = (size_t)3 * 8192 * 128 * 2;                       // qbf,kbf,vtb bf16
    b += (size_t)8192 * 128 * 4;                                 // resb fp32
    b += (size_t)nch * 8192 * 128 * 2;                           // pacc bf16
    b += (size_t)2 * nch * 8192 * 4;                             // pm, pl
    b += (size_t)2 * WTOT * 2;                                   // whi, wlo
    return b;
  };
  const int nch = (ws_size >= need(16)) ? 16 : 8;

  ushort_t* qbf = (ushort_t*)d_ws;
  ushort_t* kbf = qbf + (size_t)8192*128;
  ushort_t* vtb = kbf + (size_t)8192*128;
  float* resb = (float*)(vtb + (size_t)8192*128);
  ushort_t* pacc = (ushort_t*)(resb + (size_t)8192*128);
  float* pm   = (float*)(pacc + (size_t)nch*8192*128);
  float* pl   = pm   + (size_t)nch*8192;
  ushort_t* whi = (ushort_t*)(pl + (size_t)nch*8192);
  ushort_t* wlo = whi + WTOT;

  wconv_kernel<<<(WTOT + 255) / 256, 256, 0, stream>>>(gate_W, exp_Wr, exp_Wi,
      q_Wr, q_Wi, k_Wr, k_Wi, v_Wr, v_Wi, ctx_W, res_W, whi, wlo);
  prep_kernel<<<512, 256, 0, stream>>>(z_real, z_imag, whi, wlo, gate_b,
      ln_scale, ln_shift, mod_bias, ctx_b, res_b, qbf, kbf, vtb, resb);
  if (nch == 16){
    attn_mfma<16><<<64*16, 256, 0, stream>>>(qbf, kbf, vtb, pacc, pm, pl);
    combine_kernel<16><<<2048, 256, 0, stream>>>(pacc, pm, pl, resb,
        halt_W, halt_b, stack_W, stack_b, (float*)d_out);
  } else {
    attn_mfma<8><<<64*8, 256, 0, stream>>>(qbf, kbf, vtb, pacc, pm, pl);
    combine_kernel<8><<<2048, 256, 0, stream>>>(pacc, pm, pl, resb,
        halt_W, halt_b, stack_W, stack_b, (float*)d_out);
  }
}